// Round 5
// baseline (563.477 us; speedup 1.0000x reference)
//
#include <hip/hip_runtime.h>
#include <hip/hip_bf16.h>
#include <math.h>

#define T_LEN 4096
#define D_DIM 512
#define F_DIM 8192
#define NCHUNK 64
#define CLEN 64

typedef short short8 __attribute__((ext_vector_type(8)));
typedef float f32x4 __attribute__((ext_vector_type(4)));
typedef unsigned short u16;
typedef unsigned int u32;

// ---------------- helpers ----------------
__device__ inline float wave_sum(float v) {
#pragma unroll
  for (int o = 32; o; o >>= 1) v += __shfl_xor(v, o);
  return v;
}

__device__ inline u16 f2bf_bits(float v) {
  __hip_bfloat16 h = __float2bfloat16(v);
  return *(u16*)&h;
}

__device__ inline float bf2f(u16 u) {
  u32 x = ((u32)u) << 16;
  return *(float*)&x;
}

__device__ inline void gl_lds16(const void* g, void* l) {
  __builtin_amdgcn_global_load_lds((const __attribute__((address_space(1))) void*)g,
                                   (__attribute__((address_space(3))) void*)l, 16, 0, 0);
}

// start[] may arrive as 1-byte bools or int32 {0,1}.
__global__ void detect_start(const unsigned char* __restrict__ s8, int* __restrict__ mode) {
  __shared__ int found;
  if (threadIdx.x == 0) found = 0;
  __syncthreads();
  for (int i = threadIdx.x; i < 4096; i += 256)
    if ((i & 3) && s8[i]) found = 1;  // benign race, same value
  __syncthreads();
  if (threadIdx.x == 0) mode[0] = found;  // 1 = byte layout, 0 = int32 layout
}

__device__ inline int read_start(const unsigned char* s8, const int* s32, int mode, int t) {
  return mode ? (int)s8[t] : s32[t];
}

// ---------------- fp32 -> bf16(bits) convert (plain) ----------------
__global__ void f2bf(const float* __restrict__ s, u16* __restrict__ d, int n) {
  int i = blockIdx.x * 256 + threadIdx.x;
  if (i < n) d[i] = f2bf_bits(s[i]);
}

// fused per-layer weight conversion:
//   wcat = concat [Wtr_l; Wc_l] (128 x 512), unswizzled (BK=32 gemm)
//   w0bf: K-permute (f = r*128+2c+b <- b*4096+r*64+c) + granule swizzle by (d&7)
__global__ void k_conv(const float* __restrict__ wtr, const float* __restrict__ wc,
                       u16* __restrict__ wcat, const float* __restrict__ w0,
                       u16* __restrict__ w0bf) {
  int i = blockIdx.x * 256 + threadIdx.x;
  if (i < 128 * D_DIM) {
    float v = (i < 64 * D_DIM) ? wtr[i] : wc[i - 64 * D_DIM];
    wcat[i] = f2bf_bits(v);
  }
  int j = i - 128 * D_DIM;
  if (j >= 0 && j < D_DIM * F_DIM) {
    int d = j >> 13, f = j & 8191;
    int r = f >> 7, rem = f & 127;
    int c = rem >> 1, b = rem & 1;
    float v = w0[(size_t)d * 8192 + b * 4096 + r * 64 + c];
    w0bf[(size_t)d * 8192 + (f ^ ((d & 7) << 3))] = f2bf_bits(v);
  }
}

// ---------------- small MFMA GEMM (64x64 tile, BK=32, sync staging) — trct & W1 ----------------
template <int BM, int BN, int WR, int WC>
__global__ __launch_bounds__(256) void gemm_bt(const u16* __restrict__ A,
                                               const u16* __restrict__ B,
                                               float* __restrict__ C, int M, int N, int K) {
  constexpr int BK = 32;
  constexpr int MT = BM / (WR * 16);
  constexpr int NT = BN / (WC * 16);
  constexpr int AG = BM / 64;
  constexpr int BG = BN / 64;
  __shared__ u16 sA[BM * BK];
  __shared__ u16 sB[BN * BK];
  const int m0 = blockIdx.x * BM;
  const int n0 = blockIdx.y * BN;
  const int tid = threadIdx.x;
  const int wave = tid >> 6;
  const int lane = tid & 63;
  const int wr = wave / WC;
  const int wc = wave % WC;
  const int row_l = tid >> 2;
  const int c8 = (tid & 3) << 3;
  const int frow = lane & 15;
  const int fcol = (lane >> 4) << 3;

  f32x4 acc[MT][NT];
#pragma unroll
  for (int i = 0; i < MT; ++i)
#pragma unroll
    for (int j = 0; j < NT; ++j) acc[i][j] = (f32x4){0.f, 0.f, 0.f, 0.f};

  for (int k0 = 0; k0 < K; k0 += BK) {
#pragma unroll
    for (int j = 0; j < AG; ++j) {
      uint4 v = *(const uint4*)(A + (size_t)(m0 + j * 64 + row_l) * K + (k0 + c8));
      *(uint4*)(sA + (j * 64 + row_l) * BK + c8) = v;
    }
#pragma unroll
    for (int j = 0; j < BG; ++j) {
      uint4 v = *(const uint4*)(B + (size_t)(n0 + j * 64 + row_l) * K + (k0 + c8));
      *(uint4*)(sB + (j * 64 + row_l) * BK + c8) = v;
    }
    __syncthreads();
    short8 af[MT], bfr[NT];
#pragma unroll
    for (int i = 0; i < MT; ++i)
      af[i] = *(const short8*)(sA + (wr * MT * 16 + i * 16 + frow) * BK + fcol);
#pragma unroll
    for (int j = 0; j < NT; ++j)
      bfr[j] = *(const short8*)(sB + (wc * NT * 16 + j * 16 + frow) * BK + fcol);
#pragma unroll
    for (int i = 0; i < MT; ++i)
#pragma unroll
      for (int j = 0; j < NT; ++j)
        acc[i][j] = __builtin_amdgcn_mfma_f32_16x16x32_bf16(af[i], bfr[j], acc[i][j], 0, 0, 0);
    __syncthreads();
  }
#pragma unroll
  for (int i = 0; i < MT; ++i) {
    const int rbase = m0 + wr * MT * 16 + i * 16 + ((lane >> 4) << 2);
#pragma unroll
    for (int j = 0; j < NT; ++j) {
      const int col = n0 + wc * NT * 16 + j * 16 + (lane & 15);
#pragma unroll
      for (int rg = 0; rg < 4; ++rg) C[(size_t)(rbase + rg) * N + col] = acc[i][j][rg];
    }
  }
}

// ---------------- 128x128 MFMA GEMM, BK=64, XOR-swizzled operands, split-K, bf16 partials ----
// (retained for low-workspace fallback paths)
// A, B global layout: row-major with 16B granule g of each row stored at g ^ (row&7).
__global__ __launch_bounds__(256) void gemm128(const u16* __restrict__ A,
                                               const u16* __restrict__ B,
                                               u16* __restrict__ Cp, size_t pstride, int N,
                                               int Ktot) {
  __shared__ u16 sA[128 * 64];
  __shared__ u16 sB[128 * 64];
  const int tid = threadIdx.x;
  const int wave = tid >> 6;
  const int lane = tid & 63;
  const int wr = wave >> 1;
  const int wc = wave & 1;
  const int m0 = blockIdx.x * 128;
  const int n0 = blockIdx.y * 128;
  const int ks = blockIdx.z;
  const int Kper = Ktot / gridDim.z;
  const int kb = ks * Kper;
  const int row_s = tid >> 3;     // 0..31 staging row within 32-row group
  const int g8 = (tid & 7) << 3;  // granule offset (elems)
  const int frow = lane & 15;
  const int quad = lane >> 4;
  const int sw = frow & 7;

  f32x4 acc[4][4];
#pragma unroll
  for (int i = 0; i < 4; ++i)
#pragma unroll
    for (int j = 0; j < 4; ++j) acc[i][j] = (f32x4){0.f, 0.f, 0.f, 0.f};

  for (int k0 = kb; k0 < kb + Kper; k0 += 64) {
#pragma unroll
    for (int j = 0; j < 4; ++j) {
      gl_lds16(A + (size_t)(m0 + j * 32 + row_s) * Ktot + (k0 + g8), sA + j * 2048 + wave * 512);
      gl_lds16(B + (size_t)(n0 + j * 32 + row_s) * Ktot + (k0 + g8), sB + j * 2048 + wave * 512);
    }
    asm volatile("s_waitcnt vmcnt(0)" ::: "memory");
    __syncthreads();
#pragma unroll
    for (int kk = 0; kk < 2; ++kk) {
      const int gA = (((kk << 2) | quad) ^ sw) << 3;  // swizzled elem offset in row
      short8 af[4], bfr[4];
#pragma unroll
      for (int i = 0; i < 4; ++i)
        af[i] = *(const short8*)(sA + (wr * 64 + i * 16 + frow) * 64 + gA);
#pragma unroll
      for (int j = 0; j < 4; ++j)
        bfr[j] = *(const short8*)(sB + (wc * 64 + j * 16 + frow) * 64 + gA);
#pragma unroll
      for (int i = 0; i < 4; ++i)
#pragma unroll
        for (int j = 0; j < 4; ++j)
          acc[i][j] = __builtin_amdgcn_mfma_f32_16x16x32_bf16(af[i], bfr[j], acc[i][j], 0, 0, 0);
    }
    __syncthreads();
  }
#pragma unroll
  for (int i = 0; i < 4; ++i) {
    const int rbase = m0 + wr * 64 + i * 16 + ((lane >> 4) << 2);
#pragma unroll
    for (int j = 0; j < 4; ++j) {
      const int col = n0 + wc * 64 + j * 16 + (lane & 15);
#pragma unroll
      for (int rg = 0; rg < 4; ++rg)
        Cp[(size_t)ks * pstride + (size_t)(rbase + rg) * N + col] = f2bf_bits(acc[i][j][rg]);
    }
  }
}

// ---------------- 256x128 MFMA GEMM, B-direct / A-tribuf single-phase pipeline --------------
// v5: R4 post-mortem showed the kernel is LDS-PIPE-bound: per 64-K tile per CU the LDS
// carries A-reads 64KB (x2 waves) + B-reads 64KB (x4 waves) + 48KB stage-writes = 176KB
// (~1400-2000cyc) vs 310cyc of MFMA. Fix: B (w0bf, 8MB, L2-resident) is read DIRECTLY
// from global to registers. The global granule swizzle g^(d&7) in w0bf equals the LDS
// read swizzle (both keyed on frow&7; all row offsets are multiples of 8), so the bytes
// are identical -> bit-identical output. LDS now carries only A (64KB reads + 32KB
// writes per tile); B's 64KB rides the VMEM/L2 pipe in parallel (compiler-managed waits).
// A is TRIPLE-buffered (3 x 256x64x2B = 96KiB): stage(t+2) issued at tile t, sealed by
// the single counted vmcnt(4) at t+1 (~1 tile > 900cyc HBM latency), published by that
// tile's single barrier -> ONE barrier and ONE vmcnt per tile (never 0 until the tail).
// Seal/WAR ledger: VMEM FIFO at tile t = [stage(t+1):4][B:8][stage(t+2):4]; vmcnt(4)
// drains stage(t+1)+B, leaves stage(t+2). buf[(t+2)%3]'s last reads (tile t-1) complete
// before each reader's lgkm(0)/MFMA(t-1), which precede bar(t-1) < stage issue at t.
// MFMA order per acc element unchanged (q0,q1,q2,q3; kk ascending; KS=4; bf16 C-write)
// -> bit-identical to v2/v3/v4, absmax preserved.
__global__ __launch_bounds__(512, 2) void gemm_8ph(const u16* __restrict__ A,
                                                   const u16* __restrict__ B,
                                                   u16* __restrict__ Cp, size_t pstride, int N,
                                                   int Ktot) {
  extern __shared__ u16 smem[];
  u16* sA = smem;  // [3][256*64] A triple-buffer, 96 KiB
  const int tid = threadIdx.x;
  const int wave = tid >> 6;
  const int lane = tid & 63;
  const int wr = wave >> 1;  // 0..3 -> 64-row group
  const int wc = wave & 1;   // 0..1 -> 64-col group
  const int m0 = blockIdx.x * 256;
  const int n0 = blockIdx.y * 128;
  const int ks = blockIdx.z;
  const int Kper = Ktot / gridDim.z;
  const int kb = ks * Kper;
  const int nT = Kper >> 6;  // BK=64 tiles (32 at KS=4)
  const int r_l = tid >> 3;  // row within 64-row load group
  const int g8 = (tid & 7) << 3;
  const int frow = lane & 15;
  const int quad = lane >> 4;
  const int sw = frow & 7;
  const int o0 = (quad ^ sw) << 3;        // swizzled elem offset, kk=0
  const int o1 = ((4 | quad) ^ sw) << 3;  // swizzled elem offset, kk=1

  const u16* Abase = A + (size_t)(m0 + r_l) * Ktot + g8;
  // B row base for this lane's fragment rows: d = n0 + wc*64 + (half*32 + g*16) + frow.
  // d&7 == frow&7 (all other terms are multiples of 8) -> global swizzle == sw.
  const u16* Bbase = B + (size_t)(n0 + wc * 64 + frow) * (size_t)Ktot;

#define STAGE_A(l, k0, b) \
  gl_lds16(Abase + (size_t)(l) * 64 * Ktot + (k0), sA + (b)*16384 + (l)*4096 + wave * 512)
// 4x ds_read_b128: A frags (2 m-frags x kk=0,1) for row-half qm_ of this wave's 64 rows
#define RD_A(dst, b, qm_)                                               \
  do {                                                                  \
    const u16* _p = sA + (b)*16384 + (wr * 64 + (qm_)*32 + frow) * 64;  \
    dst[0][0] = *(const short8*)(_p + o0);                              \
    dst[0][1] = *(const short8*)(_p + o1);                              \
    dst[1][0] = *(const short8*)(_p + 1024 + o0);                       \
    dst[1][1] = *(const short8*)(_p + 1024 + o1);                       \
  } while (0)
// 4x global dwordx4 -> regs: B frags (2 n-frags x kk=0,1) for col-half half_ (L2-hot)
#define GLB_B(dst, half_)                                          \
  do {                                                             \
    const u16* _q = Bk + (size_t)((half_)*32) * Ktot;              \
    dst[0][0] = *(const short8*)(_q + o0);                         \
    dst[0][1] = *(const short8*)(_q + o1);                         \
    dst[1][0] = *(const short8*)(_q + (size_t)16 * Ktot + o0);     \
    dst[1][1] = *(const short8*)(_q + (size_t)16 * Ktot + o1);     \
  } while (0)

  f32x4 acc[4][4];
#pragma unroll
  for (int i = 0; i < 4; ++i)
#pragma unroll
    for (int j = 0; j < 4; ++j) acc[i][j] = (f32x4){0.f, 0.f, 0.f, 0.f};

  short8 af_lo[2][2];  // A rows 0..31 of wave's 64 (current tile)
  short8 af_hi[2][2];  // A rows 32..63
  short8 bfr0[2][2];   // B cols 0..31 of wave's 64
  short8 bfr1[2][2];   // B cols 32..63

  // Prologue: stage tile0 -> buf0, tile1 -> buf1; seal tile0 (leave tile1's 4 in flight).
  STAGE_A(0, kb, 0);
  STAGE_A(1, kb, 0);
  STAGE_A(2, kb, 0);
  STAGE_A(3, kb, 0);
  STAGE_A(0, kb + 64, 1);
  STAGE_A(1, kb + 64, 1);
  STAGE_A(2, kb + 64, 1);
  STAGE_A(3, kb + 64, 1);
  asm volatile("s_waitcnt vmcnt(4)" ::: "memory");
  __builtin_amdgcn_s_barrier();

  int bc = 0;  // current A buffer
  for (int t = 0; t < nT; ++t) {
    const int k0 = kb + (t << 6);
    int bs = bc + 2;
    if (bs >= 3) bs -= 3;  // stage target = buf[(t+2)%3]
    const bool nl = (t + 2 < nT);
    const u16* Bk = Bbase + k0;
    // ---- B direct loads (8 dwordx4, to regs; compiler inserts the data waits) ----
    GLB_B(bfr0, 0);
    GLB_B(bfr1, 1);
    // ---- A fragment ds_reads (buf sealed at t-1's vmcnt+barrier) ----
    RD_A(af_lo, bc, 0);
    RD_A(af_hi, bc, 1);
    // ---- stage tile t+2 (buf last read at t-1; all readers' lgkm0 preceded bar(t-1)) ----
    if (nl) {
      STAGE_A(0, k0 + 128, bs);
      STAGE_A(1, k0 + 128, bs);
      STAGE_A(2, k0 + 128, bs);
      STAGE_A(3, k0 + 128, bs);
    }
    // ---- single counted seal: drains stage(t+1)+B, leaves stage(t+2) in flight ----
    if (nl)
      asm volatile("s_waitcnt vmcnt(4)" ::: "memory");
    else
      asm volatile("s_waitcnt vmcnt(0)" ::: "memory");
    asm volatile("s_waitcnt lgkmcnt(0)" ::: "memory");
    __builtin_amdgcn_sched_barrier(0);
    // ---- 32 MFMA: q0,q1,q2,q3 (same per-acc K-order as v2/v3/v4) ----
    __builtin_amdgcn_s_setprio(1);
#pragma unroll
    for (int f = 0; f < 2; ++f)
#pragma unroll
      for (int g = 0; g < 2; ++g)
#pragma unroll
        for (int kk = 0; kk < 2; ++kk)
          acc[f][g] = __builtin_amdgcn_mfma_f32_16x16x32_bf16(af_lo[f][kk], bfr0[g][kk],
                                                              acc[f][g], 0, 0, 0);
#pragma unroll
    for (int f = 0; f < 2; ++f)
#pragma unroll
      for (int g = 0; g < 2; ++g)
#pragma unroll
        for (int kk = 0; kk < 2; ++kk)
          acc[f][2 + g] = __builtin_amdgcn_mfma_f32_16x16x32_bf16(af_lo[f][kk], bfr1[g][kk],
                                                                  acc[f][2 + g], 0, 0, 0);
#pragma unroll
    for (int f = 0; f < 2; ++f)
#pragma unroll
      for (int g = 0; g < 2; ++g)
#pragma unroll
        for (int kk = 0; kk < 2; ++kk)
          acc[2 + f][2 + g] = __builtin_amdgcn_mfma_f32_16x16x32_bf16(
              af_hi[f][kk], bfr1[g][kk], acc[2 + f][2 + g], 0, 0, 0);
#pragma unroll
    for (int f = 0; f < 2; ++f)
#pragma unroll
      for (int g = 0; g < 2; ++g)
#pragma unroll
        for (int kk = 0; kk < 2; ++kk)
          acc[2 + f][g] = __builtin_amdgcn_mfma_f32_16x16x32_bf16(af_hi[f][kk], bfr0[g][kk],
                                                                  acc[2 + f][g], 0, 0, 0);
    __builtin_amdgcn_s_setprio(0);
    // ---- single barrier per tile: publishes this wave's seal to next tile's readers ----
    __builtin_amdgcn_s_barrier();
    bc += 1;
    if (bc >= 3) bc -= 3;
  }
#undef STAGE_A
#undef RD_A
#undef GLB_B

#pragma unroll
  for (int i = 0; i < 4; ++i) {
    const int rbase = m0 + wr * 64 + i * 16 + (quad << 2);
#pragma unroll
    for (int j = 0; j < 4; ++j) {
      const int col = n0 + wc * 64 + j * 16 + frow;
#pragma unroll
      for (int rg = 0; rg < 4; ++rg)
        Cp[(size_t)ks * pstride + (size_t)(rbase + rg) * N + col] = f2bf_bits(acc[i][j][rg]);
    }
  }
}

// ---------------- p/q prep: pT=|tr| transposed, q=|ct|/(1e-8+Sp*Sq) ----------------
__global__ void prep_pq(const float* __restrict__ trct, float* __restrict__ pT,
                        float* __restrict__ q) {
  int t = blockIdx.x;
  int lane = threadIdx.x;  // 64
  float tr = trct[t * 128 + lane];
  float ct = trct[t * 128 + 64 + lane];
  float ap = fabsf(tr), aq = fabsf(ct);
  float Sp = wave_sum(ap);
  float Sq = wave_sum(aq);
  float denom = 1e-8f + Sp * Sq;
  pT[lane * T_LEN + t] = ap;  // transposed for shuffle-broadcast in scans
  q[t * 64 + lane] = aq / denom;
}

// ---------------- scan phase 1: per-chunk affine summary (A,B) ----------------
__global__ void scan_phase1(const float* __restrict__ pT, const float* __restrict__ q,
                            const unsigned char* __restrict__ st8, const int* __restrict__ st32,
                            const int* __restrict__ modep, const float* __restrict__ a,
                            const float* __restrict__ b, float4* __restrict__ chunkbuf) {
  int chunk = blockIdx.x, r = blockIdx.y, c = threadIdx.x;
  int mode = modep[0];
  int t0 = chunk * CLEN;
  float na = -fabsf(a[r]);
  float rho = __expf(na);
  float bb = b[c];
  float er = rho * __cosf(bb), ei = rho * __sinf(bb);
  float pv = pT[r * T_LEN + t0 + c];             // lane c holds p for step c
  int sv = read_start(st8, st32, mode, t0 + c);  // lane c holds start for step c
  unsigned long long bal = __ballot(sv != 0);
  float Ar, Ai;
  if (bal) {
    Ar = 0.f; Ai = 0.f;
  } else {
    float mag = __expf(64.f * na);
    float ang = 64.f * bb;
    Ar = mag * __cosf(ang);
    Ai = mag * __sinf(ang);
  }
  int L = bal ? (63 - __builtin_clzll(bal)) : 0;  // wave-uniform
  float Br = 0.f, Bi = 0.f;
  const float* qrow = q + (size_t)t0 * 64 + c;
  for (int i = L; i < CLEN; ++i) {
    float pre = __shfl(pv, i) * qrow[i * 64];
    float nBr = er * Br - ei * Bi + pre;
    Bi = er * Bi + ei * Br;
    Br = nBr;
  }
  chunkbuf[((size_t)chunk * 64 + r) * 64 + c] = make_float4(Ar, Ai, Br, Bi);
}

// ---------------- scan phase 2: sequential chunk combine ----------------
__global__ void scan_phase2(const float4* __restrict__ chunkbuf, const float* __restrict__ state,
                            float2* __restrict__ s0buf) {
  int r = blockIdx.x, c = threadIdx.x;
  float Sr = state[r * 64 + c], Si = 0.f;
  for (int k = 0; k < NCHUNK; ++k) {
    s0buf[((size_t)k * 64 + r) * 64 + c] = make_float2(Sr, Si);
    float4 ab = chunkbuf[((size_t)k * 64 + r) * 64 + c];
    float nSr = ab.x * Sr - ab.y * Si + ab.z;
    Si = ab.x * Si + ab.y * Sr + ab.w;
    Sr = nSr;
  }
}

// ---------------- scan phase 3: replay + packed log-polar features (swizzled store) ----
__global__ void scan_phase3(const float* __restrict__ pT, const float* __restrict__ q,
                            const unsigned char* __restrict__ st8, const int* __restrict__ st32,
                            const int* __restrict__ modep, const float* __restrict__ a,
                            const float* __restrict__ b, const float2* __restrict__ s0buf,
                            u32* __restrict__ scaled, int c0) {
  int chunk = c0 + blockIdx.x, r = blockIdx.y, c = threadIdx.x;
  int mode = modep[0];
  int t0 = chunk * CLEN;
  float rho = __expf(-fabsf(a[r]));
  float bb = b[c];
  float er = rho * __cosf(bb), ei = rho * __sinf(bb);
  float pv = pT[r * T_LEN + t0 + c];
  int sv = read_start(st8, st32, mode, t0 + c);
  float2 s0 = s0buf[((size_t)chunk * 64 + r) * 64 + c];
  float Sr = s0.x, Si = s0.y;
  int tl0 = (chunk - c0) * CLEN;
  const float* qrow = q + (size_t)t0 * 64 + c;
  u32* srow = scaled + (size_t)tl0 * 4096;
  const int Ldw = r * 64 + c;
#pragma unroll 4
  for (int i = 0; i < CLEN; ++i) {
    float qt = qrow[i * 64];
    float pt = __shfl(pv, i);
    int st = __shfl(sv, i);
    float pre = pt * qt;
    float cer = st ? 0.f : er;
    float cei = st ? 0.f : ei;
    float nSr = cer * Sr - cei * Si + pre;
    Si = cer * Si + cei * Sr;
    Sr = nSr;
    float m2 = fmaf(Sr, Sr, Si * Si);
    float rsq = rsqrtf(fmaxf(m2, 1e-30f));
    float m = m2 * rsq;
    float sc = __log2f(1.0f + m) * 0.6931471805599453f * rsq;
    u32 pack = ((u32)f2bf_bits(sc * Sr) << 16) | (u32)f2bf_bits(sc * Si);
    srow[(size_t)i * 4096 + (Ldw ^ ((i & 7) << 2))] = pack;
  }
}

// ---------------- LN + LeakyReLU over bf16 split-K partials -> z0bf (unswizzled) ----------------
__global__ void ln_act16(const u16* __restrict__ parts, int KS, size_t pstride,
                         const float* __restrict__ bias, const float* __restrict__ gam,
                         const float* __restrict__ bet, u16* __restrict__ zbf) {
  __shared__ float red[8];
  int t = blockIdx.x, tid = threadIdx.x;
  size_t o = (size_t)t * D_DIM + tid;
  float v0 = bias[tid];
  float v1 = bias[tid + 256];
  for (int ks = 0; ks < KS; ++ks) {
    v0 += bf2f(parts[(size_t)ks * pstride + o]);
    v1 += bf2f(parts[(size_t)ks * pstride + o + 256]);
  }
  float s = wave_sum(v0 + v1);
  if ((tid & 63) == 0) red[tid >> 6] = s;
  __syncthreads();
  float mean = (red[0] + red[1] + red[2] + red[3]) * (1.f / 512.f);
  float d0 = v0 - mean, d1 = v1 - mean;
  float s2 = wave_sum(d0 * d0 + d1 * d1);
  if ((tid & 63) == 0) red[4 + (tid >> 6)] = s2;
  __syncthreads();
  float var = (red[4] + red[5] + red[6] + red[7]) * (1.f / 512.f);
  float rstd = rsqrtf(var + 1e-5f);
  float z0 = d0 * rstd * gam[tid] + bet[tid];
  float z1 = d1 * rstd * gam[tid + 256] + bet[tid + 256];
  z0 = z0 > 0.f ? z0 : 0.01f * z0;
  z1 = z1 > 0.f ? z1 : 0.01f * z1;
  zbf[o] = f2bf_bits(z0);
  zbf[o + 256] = f2bf_bits(z1);
}

// ---------------- LN + LeakyReLU over fp32 y (W1 epilogue) ----------------
__global__ void ln_act32(const float* __restrict__ y, const float* __restrict__ bias,
                         const float* __restrict__ gam, const float* __restrict__ bet,
                         const float* __restrict__ xsrc, float* __restrict__ xdst,
                         u16* __restrict__ xbf_next, float* __restrict__ finout) {
  __shared__ float red[8];
  int t = blockIdx.x, tid = threadIdx.x;
  size_t o = (size_t)t * D_DIM + tid;
  float v0 = y[o] + bias[tid];
  float v1 = y[o + 256] + bias[tid + 256];
  float s = wave_sum(v0 + v1);
  if ((tid & 63) == 0) red[tid >> 6] = s;
  __syncthreads();
  float mean = (red[0] + red[1] + red[2] + red[3]) * (1.f / 512.f);
  float d0 = v0 - mean, d1 = v1 - mean;
  float s2 = wave_sum(d0 * d0 + d1 * d1);
  if ((tid & 63) == 0) red[4 + (tid >> 6)] = s2;
  __syncthreads();
  float var = (red[4] + red[5] + red[6] + red[7]) * (1.f / 512.f);
  float rstd = rsqrtf(var + 1e-5f);
  float z0 = d0 * rstd * gam[tid] + bet[tid];
  float z1 = d1 * rstd * gam[tid + 256] + bet[tid + 256];
  z0 = z0 > 0.f ? z0 : 0.01f * z0;
  z1 = z1 > 0.f ? z1 : 0.01f * z1;
  if (xdst) {
    float x0 = xsrc[o] + z0, x1 = xsrc[o + 256] + z1;
    xdst[o] = x0;
    xdst[o + 256] = x1;
    xbf_next[o] = f2bf_bits(x0);
    xbf_next[o + 256] = f2bf_bits(x1);
  }
  if (finout) {
    finout[o] = z0;
    finout[o + 256] = z1;
  }
}

__global__ void err_signal(float* __restrict__ out, float code) {
  if (threadIdx.x == 0) out[0] = code;
}

// ---------------- host launch ----------------
extern "C" void kernel_launch(void* const* d_in, const int* in_sizes, int n_in, void* d_out,
                              int out_size, void* d_ws, size_t ws_size, hipStream_t stream) {
  const float* x_in = (const float*)d_in[0];
  const float* state = (const float*)d_in[1];
  const unsigned char* start8 = (const unsigned char*)d_in[2];
  const int* start32 = (const int*)d_in[2];
  const float* Wtr = (const float*)d_in[3];
  const float* Wc = (const float*)d_in[4];
  const float* a_in = (const float*)d_in[5];
  const float* b_in = (const float*)d_in[6];
  const float* W0 = (const float*)d_in[7];
  const float* b0 = (const float*)d_in[8];
  const float* g0 = (const float*)d_in[9];
  const float* beta0 = (const float*)d_in[10];
  const float* W1 = (const float*)d_in[11];
  const float* b1 = (const float*)d_in[12];
  const float* g1 = (const float*)d_in[13];
  const float* beta1 = (const float*)d_in[14];
  float* out = (float*)d_out;

  // one-time: allow 96 KiB dynamic LDS for the B-direct GEMM
  static int attr_state = 0;  // 0 unset, 1 ok, -1 failed
  if (attr_state == 0)
    attr_state = (hipFuncSetAttribute((const void*)gemm_8ph,
                                      hipFuncAttributeMaxDynamicSharedMemorySize,
                                      98304) == hipSuccess)
                     ? 1
                     : -1;
  const bool attr_ok = (attr_state == 1);

  char* w = (char*)d_ws;
  auto alloc = [&](size_t bytes) {
    char* ptr = w;
    w += (bytes + 255) & ~(size_t)255;
    return ptr;
  };
  float* x_ws = (float*)alloc(4ull * T_LEN * D_DIM);            // 8 MB
  u16* xbf = (u16*)alloc(2ull * T_LEN * D_DIM);                 // 4 MB
  u16* wcat = (u16*)alloc(2ull * 128 * D_DIM);                  // 128 KB
  u16* w0bf = (u16*)alloc(2ull * D_DIM * F_DIM);                // 8 MB (per-layer)
  u16* w1bf = (u16*)alloc(2ull * 3 * D_DIM * D_DIM);            // 1.5 MB (all layers)
  float* trct = (float*)alloc(4ull * T_LEN * 128);              // 2 MB
  float* pTbuf = (float*)alloc(4ull * T_LEN * 64);              // 1 MB
  float* qbuf = (float*)alloc(4ull * T_LEN * 64);               // 1 MB
  float4* chunkbuf = (float4*)alloc(16ull * NCHUNK * 64 * 64);  // 4 MB
  float2* s0buf = (float2*)alloc(8ull * NCHUNK * 64 * 64);      // 2 MB
  u16* z0bf = (u16*)alloc(2ull * T_LEN * D_DIM);                // 4 MB
  float* ybuf = (float*)alloc(4ull * T_LEN * D_DIM);            // 8 MB (W1 out)
  int* modep = (int*)alloc(256);
  size_t base1 = (size_t)(w - (char*)d_ws);

  if (n_in != 15) {
    err_signal<<<1, 64, 0, stream>>>(out, 9e6f + 1000.f * n_in);
    return;
  }
  const size_t MB = 1ull << 20;
  const size_t pstride = (size_t)T_LEN * D_DIM;  // elements per partial slab
  int KS, nseg;
  if (ws_size >= base1 + 16 * MB + 64 * MB) { KS = 4; nseg = 1; }
  else if (ws_size >= base1 + 16 * MB + 32 * MB) { KS = 4; nseg = 2; }
  else if (ws_size >= base1 + 8 * MB + 32 * MB) { KS = 2; nseg = 2; }
  else if (ws_size >= base1 + 8 * MB + 16 * MB) { KS = 2; nseg = 4; }
  else if (ws_size >= base1 + 4 * MB + 16 * MB) { KS = 1; nseg = 4; }
  else {
    err_signal<<<1, 64, 0, stream>>>(out, 9e6f);
    return;
  }
  const int seg_rows = T_LEN / nseg;
  const int seg_chunks = NCHUNK / nseg;
  u16* ypart = (u16*)alloc(2ull * KS * pstride);
  u16* scaled = (u16*)alloc(2ull * seg_rows * F_DIM);

  const bool use8 = (nseg == 1) && attr_ok;  // seg_rows==4096 -> grid.x=16

  detect_start<<<1, 256, 0, stream>>>(start8, modep);
  f2bf<<<(T_LEN * D_DIM) / 256, 256, 0, stream>>>(x_in, xbf, T_LEN * D_DIM);
  f2bf<<<(3 * D_DIM * D_DIM) / 256, 256, 0, stream>>>(W1, w1bf, 3 * D_DIM * D_DIM);

  for (int l = 0; l < 3; ++l) {
    const float* Wtr_l = Wtr + (size_t)l * 64 * D_DIM;
    const float* Wc_l = Wc + (size_t)l * 64 * D_DIM;
    const float* a_l = a_in + l * 64;
    const float* b_l = b_in + l * 64;
    const float* W0_l = W0 + (size_t)l * D_DIM * F_DIM;
    const u16* w1bf_l = w1bf + (size_t)l * D_DIM * D_DIM;
    const float* state_l = state + (size_t)l * 64 * 64;
    const float* xsrc = (l == 0) ? x_in : x_ws;

    k_conv<<<(128 * D_DIM + D_DIM * F_DIM) / 256, 256, 0, stream>>>(Wtr_l, Wc_l, wcat, W0_l,
                                                                    w0bf);
    // trct (4096 x 128) = xbf @ wcat^T
    gemm_bt<64, 64, 2, 2><<<dim3(T_LEN / 64, 2), 256, 0, stream>>>(xbf, wcat, trct, T_LEN, 128,
                                                                   D_DIM);
    prep_pq<<<T_LEN, 64, 0, stream>>>(trct, pTbuf, qbuf);
    scan_phase1<<<dim3(NCHUNK, 64), 64, 0, stream>>>(pTbuf, qbuf, start8, start32, modep, a_l,
                                                     b_l, chunkbuf);
    scan_phase2<<<64, 64, 0, stream>>>(chunkbuf, state_l, s0buf);

    for (int h = 0; h < nseg; ++h) {
      scan_phase3<<<dim3(seg_chunks, 64), 64, 0, stream>>>(pTbuf, qbuf, start8, start32, modep,
                                                           a_l, b_l, s0buf, (u32*)scaled,
                                                           h * seg_chunks);
      if (use8)
        gemm_8ph<<<dim3(seg_rows / 256, D_DIM / 128, KS), 512, 98304, stream>>>(
            scaled, w0bf, ypart + (size_t)h * seg_rows * D_DIM, pstride, D_DIM, F_DIM);
      else
        gemm128<<<dim3(seg_rows / 128, D_DIM / 128, KS), 256, 0, stream>>>(
            scaled, w0bf, ypart + (size_t)h * seg_rows * D_DIM, pstride, D_DIM, F_DIM);
    }
    ln_act16<<<T_LEN, 256, 0, stream>>>(ypart, KS, pstride, b0 + l * D_DIM, g0 + l * D_DIM,
                                        beta0 + l * D_DIM, z0bf);
    // y2 = z0 (4096x512) @ W1 (512x512)^T — no split-K, grid 64x8 = 512 blocks
    gemm_bt<64, 64, 2, 2><<<dim3(T_LEN / 64, D_DIM / 64), 256, 0, stream>>>(z0bf, w1bf_l, ybuf,
                                                                            T_LEN, D_DIM, D_DIM);
    ln_act32<<<T_LEN, 256, 0, stream>>>(ybuf, b1 + l * D_DIM, g1 + l * D_DIM, beta1 + l * D_DIM,
                                        (l < 2) ? xsrc : nullptr, (l < 2) ? x_ws : nullptr,
                                        (l < 2) ? xbf : nullptr, (l == 2) ? out : nullptr);
  }
}

// Round 6
// 548.725 us; speedup vs baseline: 1.0269x; 1.0269x over previous
//
#include <hip/hip_runtime.h>
#include <hip/hip_bf16.h>
#include <math.h>

#define T_LEN 4096
#define D_DIM 512
#define F_DIM 8192
#define NCHUNK 64
#define CLEN 64

typedef short short8 __attribute__((ext_vector_type(8)));
typedef float f32x4 __attribute__((ext_vector_type(4)));
typedef unsigned short u16;
typedef unsigned int u32;

// ---------------- helpers ----------------
__device__ inline float wave_sum(float v) {
#pragma unroll
  for (int o = 32; o; o >>= 1) v += __shfl_xor(v, o);
  return v;
}

__device__ inline u16 f2bf_bits(float v) {
  __hip_bfloat16 h = __float2bfloat16(v);
  return *(u16*)&h;
}

__device__ inline float bf2f(u16 u) {
  u32 x = ((u32)u) << 16;
  return *(float*)&x;
}

__device__ inline void gl_lds16(const void* g, void* l) {
  __builtin_amdgcn_global_load_lds((const __attribute__((address_space(1))) void*)g,
                                   (__attribute__((address_space(3))) void*)l, 16, 0, 0);
}

// start[] may arrive as 1-byte bools or int32 {0,1}.
__global__ void detect_start(const unsigned char* __restrict__ s8, int* __restrict__ mode) {
  __shared__ int found;
  if (threadIdx.x == 0) found = 0;
  __syncthreads();
  for (int i = threadIdx.x; i < 4096; i += 256)
    if ((i & 3) && s8[i]) found = 1;  // benign race, same value
  __syncthreads();
  if (threadIdx.x == 0) mode[0] = found;  // 1 = byte layout, 0 = int32 layout
}

__device__ inline int read_start(const unsigned char* s8, const int* s32, int mode, int t) {
  return mode ? (int)s8[t] : s32[t];
}

// ---------------- fp32 -> bf16(bits) convert (plain) ----------------
__global__ void f2bf(const float* __restrict__ s, u16* __restrict__ d, int n) {
  int i = blockIdx.x * 256 + threadIdx.x;
  if (i < n) d[i] = f2bf_bits(s[i]);
}

// fused per-layer weight conversion:
//   wcat = concat [Wtr_l; Wc_l] (128 x 512), unswizzled (BK=32 gemm)
//   w0bf: K-permute (f = r*128+2c+b <- b*4096+r*64+c) + granule swizzle by (d&7)
__global__ void k_conv(const float* __restrict__ wtr, const float* __restrict__ wc,
                       u16* __restrict__ wcat, const float* __restrict__ w0,
                       u16* __restrict__ w0bf) {
  int i = blockIdx.x * 256 + threadIdx.x;
  if (i < 128 * D_DIM) {
    float v = (i < 64 * D_DIM) ? wtr[i] : wc[i - 64 * D_DIM];
    wcat[i] = f2bf_bits(v);
  }
  int j = i - 128 * D_DIM;
  if (j >= 0 && j < D_DIM * F_DIM) {
    int d = j >> 13, f = j & 8191;
    int r = f >> 7, rem = f & 127;
    int c = rem >> 1, b = rem & 1;
    float v = w0[(size_t)d * 8192 + b * 4096 + r * 64 + c];
    w0bf[(size_t)d * 8192 + (f ^ ((d & 7) << 3))] = f2bf_bits(v);
  }
}

// ---------------- small MFMA GEMM (64x64 tile, BK=32, sync staging) — trct & W1 ----------------
template <int BM, int BN, int WR, int WC>
__global__ __launch_bounds__(256) void gemm_bt(const u16* __restrict__ A,
                                               const u16* __restrict__ B,
                                               float* __restrict__ C, int M, int N, int K) {
  constexpr int BK = 32;
  constexpr int MT = BM / (WR * 16);
  constexpr int NT = BN / (WC * 16);
  constexpr int AG = BM / 64;
  constexpr int BG = BN / 64;
  __shared__ u16 sA[BM * BK];
  __shared__ u16 sB[BN * BK];
  const int m0 = blockIdx.x * BM;
  const int n0 = blockIdx.y * BN;
  const int tid = threadIdx.x;
  const int wave = tid >> 6;
  const int lane = tid & 63;
  const int wr = wave / WC;
  const int wc = wave % WC;
  const int row_l = tid >> 2;
  const int c8 = (tid & 3) << 3;
  const int frow = lane & 15;
  const int fcol = (lane >> 4) << 3;

  f32x4 acc[MT][NT];
#pragma unroll
  for (int i = 0; i < MT; ++i)
#pragma unroll
    for (int j = 0; j < NT; ++j) acc[i][j] = (f32x4){0.f, 0.f, 0.f, 0.f};

  for (int k0 = 0; k0 < K; k0 += BK) {
#pragma unroll
    for (int j = 0; j < AG; ++j) {
      uint4 v = *(const uint4*)(A + (size_t)(m0 + j * 64 + row_l) * K + (k0 + c8));
      *(uint4*)(sA + (j * 64 + row_l) * BK + c8) = v;
    }
#pragma unroll
    for (int j = 0; j < BG; ++j) {
      uint4 v = *(const uint4*)(B + (size_t)(n0 + j * 64 + row_l) * K + (k0 + c8));
      *(uint4*)(sB + (j * 64 + row_l) * BK + c8) = v;
    }
    __syncthreads();
    short8 af[MT], bfr[NT];
#pragma unroll
    for (int i = 0; i < MT; ++i)
      af[i] = *(const short8*)(sA + (wr * MT * 16 + i * 16 + frow) * BK + fcol);
#pragma unroll
    for (int j = 0; j < NT; ++j)
      bfr[j] = *(const short8*)(sB + (wc * NT * 16 + j * 16 + frow) * BK + fcol);
#pragma unroll
    for (int i = 0; i < MT; ++i)
#pragma unroll
      for (int j = 0; j < NT; ++j)
        acc[i][j] = __builtin_amdgcn_mfma_f32_16x16x32_bf16(af[i], bfr[j], acc[i][j], 0, 0, 0);
    __syncthreads();
  }
#pragma unroll
  for (int i = 0; i < MT; ++i) {
    const int rbase = m0 + wr * MT * 16 + i * 16 + ((lane >> 4) << 2);
#pragma unroll
    for (int j = 0; j < NT; ++j) {
      const int col = n0 + wc * NT * 16 + j * 16 + (lane & 15);
#pragma unroll
      for (int rg = 0; rg < 4; ++rg) C[(size_t)(rbase + rg) * N + col] = acc[i][j][rg];
    }
  }
}

// ---------------- 128x128 MFMA GEMM, BK=64, XOR-swizzled operands, split-K, bf16 partials ----
// (retained for low-workspace fallback paths)
// A, B global layout: row-major with 16B granule g of each row stored at g ^ (row&7).
__global__ __launch_bounds__(256) void gemm128(const u16* __restrict__ A,
                                               const u16* __restrict__ B,
                                               u16* __restrict__ Cp, size_t pstride, int N,
                                               int Ktot) {
  __shared__ u16 sA[128 * 64];
  __shared__ u16 sB[128 * 64];
  const int tid = threadIdx.x;
  const int wave = tid >> 6;
  const int lane = tid & 63;
  const int wr = wave >> 1;
  const int wc = wave & 1;
  const int m0 = blockIdx.x * 128;
  const int n0 = blockIdx.y * 128;
  const int ks = blockIdx.z;
  const int Kper = Ktot / gridDim.z;
  const int kb = ks * Kper;
  const int row_s = tid >> 3;     // 0..31 staging row within 32-row group
  const int g8 = (tid & 7) << 3;  // granule offset (elems)
  const int frow = lane & 15;
  const int quad = lane >> 4;
  const int sw = frow & 7;

  f32x4 acc[4][4];
#pragma unroll
  for (int i = 0; i < 4; ++i)
#pragma unroll
    for (int j = 0; j < 4; ++j) acc[i][j] = (f32x4){0.f, 0.f, 0.f, 0.f};

  for (int k0 = kb; k0 < kb + Kper; k0 += 64) {
#pragma unroll
    for (int j = 0; j < 4; ++j) {
      gl_lds16(A + (size_t)(m0 + j * 32 + row_s) * Ktot + (k0 + g8), sA + j * 2048 + wave * 512);
      gl_lds16(B + (size_t)(n0 + j * 32 + row_s) * Ktot + (k0 + g8), sB + j * 2048 + wave * 512);
    }
    asm volatile("s_waitcnt vmcnt(0)" ::: "memory");
    __syncthreads();
#pragma unroll
    for (int kk = 0; kk < 2; ++kk) {
      const int gA = (((kk << 2) | quad) ^ sw) << 3;  // swizzled elem offset in row
      short8 af[4], bfr[4];
#pragma unroll
      for (int i = 0; i < 4; ++i)
        af[i] = *(const short8*)(sA + (wr * 64 + i * 16 + frow) * 64 + gA);
#pragma unroll
      for (int j = 0; j < 4; ++j)
        bfr[j] = *(const short8*)(sB + (wc * 64 + j * 16 + frow) * 64 + gA);
#pragma unroll
      for (int i = 0; i < 4; ++i)
#pragma unroll
        for (int j = 0; j < 4; ++j)
          acc[i][j] = __builtin_amdgcn_mfma_f32_16x16x32_bf16(af[i], bfr[j], acc[i][j], 0, 0, 0);
    }
    __syncthreads();
  }
#pragma unroll
  for (int i = 0; i < 4; ++i) {
    const int rbase = m0 + wr * 64 + i * 16 + ((lane >> 4) << 2);
#pragma unroll
    for (int j = 0; j < 4; ++j) {
      const int col = n0 + wc * 64 + j * 16 + (lane & 15);
#pragma unroll
      for (int rg = 0; rg < 4; ++rg)
        Cp[(size_t)ks * pstride + (size_t)(rbase + rg) * N + col] = f2bf_bits(acc[i][j][rg]);
    }
  }
}

// ---------------- 256x128 MFMA GEMM, B-direct with 1-tile register prefetch (v6) ------------
// R5 post-mortem: v5's B-direct regressed (66us) because B(t) was issued AND consumed in
// tile t — the seal sat behind B's L2 round-trip every tile. v6 keeps B-direct (LDS/tile
// 176KB -> 96KB, the R4 bound) but prefetches B(t+1) into a PING-PONG register set during
// tile t, so the per-tile counted seal vmcnt(12) only drains loads issued a full tile
// (~1500cyc > 900cyc HBM) earlier. FIFO at tile t's seal:
//   [B(t):8, stage(t+1):4 | B(t+1):8, stage(t+2):4]  -> vmcnt(12) drains the first pair.
// Tail: vmcnt(8) at t=nT-2, vmcnt(0) at t=nT-1. Prologue: stage(0), B(0), stage(1),
// vmcnt(4). A stays triple-buffered (3x32KB=96KiB). One barrier + one vmcnt per tile.
// Loop unrolled x2 with NAMED B reg sets (no dynamic indexing -> no scratch).
// WAR: stage targets buf[(t+2)%3], last read at tile t-1; all readers' lgkm(0) preceded
// t-1's trailing barrier, which precedes the stage issue. B bytes are identical to the
// LDS path (w0bf global granule swizzle g^(d&7) == read swizzle since d&7==frow&7; proven
// bit-identical by v5's pass). MFMA order per acc element unchanged (q0,q1,q2,q3; kk
// ascending; KS=4; bf16 C-write) -> bit-identical output.
__global__ __launch_bounds__(512, 2) void gemm_8ph(const u16* __restrict__ A,
                                                   const u16* __restrict__ B,
                                                   u16* __restrict__ Cp, size_t pstride, int N,
                                                   int Ktot) {
  extern __shared__ u16 smem[];
  u16* sA = smem;  // [3][256*64] A triple-buffer, 96 KiB
  const int tid = threadIdx.x;
  const int wave = tid >> 6;
  const int lane = tid & 63;
  const int wr = wave >> 1;  // 0..3 -> 64-row group
  const int wc = wave & 1;   // 0..1 -> 64-col group
  const int m0 = blockIdx.x * 256;
  const int n0 = blockIdx.y * 128;
  const int ks = blockIdx.z;
  const int Kper = Ktot / gridDim.z;
  const int kb = ks * Kper;
  const int nT = Kper >> 6;  // BK=64 tiles (32 at KS=4) — even
  const int r_l = tid >> 3;  // row within 64-row load group
  const int g8 = (tid & 7) << 3;
  const int frow = lane & 15;
  const int quad = lane >> 4;
  const int sw = frow & 7;
  const int o0 = (quad ^ sw) << 3;        // swizzled elem offset, kk=0
  const int o1 = ((4 | quad) ^ sw) << 3;  // swizzled elem offset, kk=1

  const u16* Abase = A + (size_t)(m0 + r_l) * Ktot + g8;
  // B fragment rows: d = n0 + wc*64 + {0,16,32,48} + frow; d&7 == frow&7 -> swizzle == sw.
  const u16* Bbase = B + (size_t)(n0 + wc * 64 + frow) * (size_t)Ktot;

#define STAGE_A(l, k0, b) \
  gl_lds16(Abase + (size_t)(l) * 64 * Ktot + (k0), sA + (b)*16384 + (l)*4096 + wave * 512)
#define STAGE4(k0, b)    \
  do {                   \
    STAGE_A(0, k0, b);   \
    STAGE_A(1, k0, b);   \
    STAGE_A(2, k0, b);   \
    STAGE_A(3, k0, b);   \
  } while (0)
// 4x ds_read_b128: A frags (2 m-frags x kk=0,1) for row-half qm_ of this wave's 64 rows
#define RD_A(dst, b, qm_)                                               \
  do {                                                                  \
    const u16* _p = sA + (b)*16384 + (wr * 64 + (qm_)*32 + frow) * 64;  \
    dst[0][0] = *(const short8*)(_p + o0);                              \
    dst[0][1] = *(const short8*)(_p + o1);                              \
    dst[1][0] = *(const short8*)(_p + 1024 + o0);                       \
    dst[1][1] = *(const short8*)(_p + 1024 + o1);                       \
  } while (0)
// 8x global dwordx4 -> regs: both B col-halves for k-offset kadd (L2-hot)
#define GLB_B(d0_, d1_, kadd)                                      \
  do {                                                             \
    const u16* _q = Bbase + (kadd);                                \
    d0_[0][0] = *(const short8*)(_q + o0);                         \
    d0_[0][1] = *(const short8*)(_q + o1);                         \
    d0_[1][0] = *(const short8*)(_q + (size_t)16 * Ktot + o0);     \
    d0_[1][1] = *(const short8*)(_q + (size_t)16 * Ktot + o1);     \
    d1_[0][0] = *(const short8*)(_q + (size_t)32 * Ktot + o0);     \
    d1_[0][1] = *(const short8*)(_q + (size_t)32 * Ktot + o1);     \
    d1_[1][0] = *(const short8*)(_q + (size_t)48 * Ktot + o0);     \
    d1_[1][1] = *(const short8*)(_q + (size_t)48 * Ktot + o1);     \
  } while (0)
// 32 MFMA: q0(lo x b0), q1(lo x b1), q2(hi x b1), q3(hi x b0) — kk ascending
#define MFMA32(b0_, b1_)                                                                 \
  do {                                                                                   \
    _Pragma("unroll") for (int f = 0; f < 2; ++f)                                        \
        _Pragma("unroll") for (int g = 0; g < 2; ++g)                                    \
            _Pragma("unroll") for (int kk = 0; kk < 2; ++kk) acc[f][g] =                 \
                __builtin_amdgcn_mfma_f32_16x16x32_bf16(af_lo[f][kk], b0_[g][kk],        \
                                                        acc[f][g], 0, 0, 0);             \
    _Pragma("unroll") for (int f = 0; f < 2; ++f)                                        \
        _Pragma("unroll") for (int g = 0; g < 2; ++g)                                    \
            _Pragma("unroll") for (int kk = 0; kk < 2; ++kk) acc[f][2 + g] =             \
                __builtin_amdgcn_mfma_f32_16x16x32_bf16(af_lo[f][kk], b1_[g][kk],        \
                                                        acc[f][2 + g], 0, 0, 0);         \
    _Pragma("unroll") for (int f = 0; f < 2; ++f)                                        \
        _Pragma("unroll") for (int g = 0; g < 2; ++g)                                    \
            _Pragma("unroll") for (int kk = 0; kk < 2; ++kk) acc[2 + f][2 + g] =         \
                __builtin_amdgcn_mfma_f32_16x16x32_bf16(af_hi[f][kk], b1_[g][kk],        \
                                                        acc[2 + f][2 + g], 0, 0, 0);     \
    _Pragma("unroll") for (int f = 0; f < 2; ++f)                                        \
        _Pragma("unroll") for (int g = 0; g < 2; ++g)                                    \
            _Pragma("unroll") for (int kk = 0; kk < 2; ++kk) acc[2 + f][g] =             \
                __builtin_amdgcn_mfma_f32_16x16x32_bf16(af_hi[f][kk], b0_[g][kk],        \
                                                        acc[2 + f][g], 0, 0, 0);         \
  } while (0)

  f32x4 acc[4][4];
#pragma unroll
  for (int i = 0; i < 4; ++i)
#pragma unroll
    for (int j = 0; j < 4; ++j) acc[i][j] = (f32x4){0.f, 0.f, 0.f, 0.f};

  short8 af_lo[2][2], af_hi[2][2];       // A frags, current tile
  short8 bA0[2][2], bA1[2][2];           // B reg set A (even tiles)
  short8 bB0[2][2], bB1[2][2];           // B reg set B (odd tiles)

  // Prologue: stage(0)->buf0, B(0)->setA, stage(1)->buf1; seal stage(0)+B(0).
  STAGE4(kb, 0);
  GLB_B(bA0, bA1, kb);
  STAGE4(kb + 64, 1);
  __builtin_amdgcn_sched_barrier(0);
  asm volatile("s_waitcnt vmcnt(4)" ::: "memory");  // leaves stage(1) in flight
  __builtin_amdgcn_s_barrier();
  __builtin_amdgcn_sched_barrier(0);

  int bc = 0;  // buffer of the even tile of the current pair
  for (int t = 0; t < nT; t += 2) {
    const int k0 = kb + (t << 6);
    const bool nl = (t + 2 < nT);
    int b1 = bc + 1;
    if (b1 >= 3) b1 -= 3;
    int b2 = bc + 2;
    if (b2 >= 3) b2 -= 3;

    // ======== even tile t: consume B setA; prefetch B(t+1)->setB; stage(t+2) ========
    RD_A(af_lo, bc, 0);
    RD_A(af_hi, bc, 1);
    GLB_B(bB0, bB1, k0 + 64);  // B(t+1): t+1 <= nT-1 always
    if (nl) STAGE4(k0 + 128, b2);
    __builtin_amdgcn_sched_barrier(0);
    if (nl)
      asm volatile("s_waitcnt vmcnt(12)" ::: "memory");  // drain B(t)+stage(t+1)
    else
      asm volatile("s_waitcnt vmcnt(8)" ::: "memory");   // no stage(t+2) in FIFO
    asm volatile("s_waitcnt lgkmcnt(0)" ::: "memory");
    __builtin_amdgcn_sched_barrier(0);
    __builtin_amdgcn_s_setprio(1);
    MFMA32(bA0, bA1);
    __builtin_amdgcn_s_setprio(0);
    __builtin_amdgcn_s_barrier();
    __builtin_amdgcn_sched_barrier(0);

    // ======== odd tile t+1: consume B setB; prefetch B(t+2)->setA; stage(t+3) ========
    RD_A(af_lo, b1, 0);
    RD_A(af_hi, b1, 1);
    if (nl) {
      GLB_B(bA0, bA1, k0 + 128);  // B(t+2)
      STAGE4(k0 + 192, bc);       // stage(t+3) -> buf[(t+3)%3] = bc (read finished even tile)
    }
    __builtin_amdgcn_sched_barrier(0);
    if (nl)
      asm volatile("s_waitcnt vmcnt(12)" ::: "memory");  // drain B(t+1)+stage(t+2)
    else
      asm volatile("s_waitcnt vmcnt(0)" ::: "memory");   // final tile: drain B(t+1)
    asm volatile("s_waitcnt lgkmcnt(0)" ::: "memory");
    __builtin_amdgcn_sched_barrier(0);
    __builtin_amdgcn_s_setprio(1);
    MFMA32(bB0, bB1);
    __builtin_amdgcn_s_setprio(0);
    __builtin_amdgcn_s_barrier();
    __builtin_amdgcn_sched_barrier(0);

    bc = b2;  // advance two tiles
  }
#undef STAGE_A
#undef STAGE4
#undef RD_A
#undef GLB_B
#undef MFMA32

#pragma unroll
  for (int i = 0; i < 4; ++i) {
    const int rbase = m0 + wr * 64 + i * 16 + (quad << 2);
#pragma unroll
    for (int j = 0; j < 4; ++j) {
      const int col = n0 + wc * 64 + j * 16 + frow;
#pragma unroll
      for (int rg = 0; rg < 4; ++rg)
        Cp[(size_t)ks * pstride + (size_t)(rbase + rg) * N + col] = f2bf_bits(acc[i][j][rg]);
    }
  }
}

// ---------------- p/q prep: pT=|tr| transposed, q=|ct|/(1e-8+Sp*Sq) ----------------
__global__ void prep_pq(const float* __restrict__ trct, float* __restrict__ pT,
                        float* __restrict__ q) {
  int t = blockIdx.x;
  int lane = threadIdx.x;  // 64
  float tr = trct[t * 128 + lane];
  float ct = trct[t * 128 + 64 + lane];
  float ap = fabsf(tr), aq = fabsf(ct);
  float Sp = wave_sum(ap);
  float Sq = wave_sum(aq);
  float denom = 1e-8f + Sp * Sq;
  pT[lane * T_LEN + t] = ap;  // transposed for shuffle-broadcast in scans
  q[t * 64 + lane] = aq / denom;
}

// ---------------- scan phase 1: per-chunk affine summary (A,B) ----------------
__global__ void scan_phase1(const float* __restrict__ pT, const float* __restrict__ q,
                            const unsigned char* __restrict__ st8, const int* __restrict__ st32,
                            const int* __restrict__ modep, const float* __restrict__ a,
                            const float* __restrict__ b, float4* __restrict__ chunkbuf) {
  int chunk = blockIdx.x, r = blockIdx.y, c = threadIdx.x;
  int mode = modep[0];
  int t0 = chunk * CLEN;
  float na = -fabsf(a[r]);
  float rho = __expf(na);
  float bb = b[c];
  float er = rho * __cosf(bb), ei = rho * __sinf(bb);
  float pv = pT[r * T_LEN + t0 + c];             // lane c holds p for step c
  int sv = read_start(st8, st32, mode, t0 + c);  // lane c holds start for step c
  unsigned long long bal = __ballot(sv != 0);
  float Ar, Ai;
  if (bal) {
    Ar = 0.f; Ai = 0.f;
  } else {
    float mag = __expf(64.f * na);
    float ang = 64.f * bb;
    Ar = mag * __cosf(ang);
    Ai = mag * __sinf(ang);
  }
  int L = bal ? (63 - __builtin_clzll(bal)) : 0;  // wave-uniform
  float Br = 0.f, Bi = 0.f;
  const float* qrow = q + (size_t)t0 * 64 + c;
  for (int i = L; i < CLEN; ++i) {
    float pre = __shfl(pv, i) * qrow[i * 64];
    float nBr = er * Br - ei * Bi + pre;
    Bi = er * Bi + ei * Br;
    Br = nBr;
  }
  chunkbuf[((size_t)chunk * 64 + r) * 64 + c] = make_float4(Ar, Ai, Br, Bi);
}

// ---------------- scan phase 2: sequential chunk combine ----------------
__global__ void scan_phase2(const float4* __restrict__ chunkbuf, const float* __restrict__ state,
                            float2* __restrict__ s0buf) {
  int r = blockIdx.x, c = threadIdx.x;
  float Sr = state[r * 64 + c], Si = 0.f;
  for (int k = 0; k < NCHUNK; ++k) {
    s0buf[((size_t)k * 64 + r) * 64 + c] = make_float2(Sr, Si);
    float4 ab = chunkbuf[((size_t)k * 64 + r) * 64 + c];
    float nSr = ab.x * Sr - ab.y * Si + ab.z;
    Si = ab.x * Si + ab.y * Sr + ab.w;
    Sr = nSr;
  }
}

// ---------------- scan phase 3: replay + packed log-polar features (swizzled store) ----
__global__ void scan_phase3(const float* __restrict__ pT, const float* __restrict__ q,
                            const unsigned char* __restrict__ st8, const int* __restrict__ st32,
                            const int* __restrict__ modep, const float* __restrict__ a,
                            const float* __restrict__ b, const float2* __restrict__ s0buf,
                            u32* __restrict__ scaled, int c0) {
  int chunk = c0 + blockIdx.x, r = blockIdx.y, c = threadIdx.x;
  int mode = modep[0];
  int t0 = chunk * CLEN;
  float rho = __expf(-fabsf(a[r]));
  float bb = b[c];
  float er = rho * __cosf(bb), ei = rho * __sinf(bb);
  float pv = pT[r * T_LEN + t0 + c];
  int sv = read_start(st8, st32, mode, t0 + c);
  float2 s0 = s0buf[((size_t)chunk * 64 + r) * 64 + c];
  float Sr = s0.x, Si = s0.y;
  int tl0 = (chunk - c0) * CLEN;
  const float* qrow = q + (size_t)t0 * 64 + c;
  u32* srow = scaled + (size_t)tl0 * 4096;
  const int Ldw = r * 64 + c;
#pragma unroll 4
  for (int i = 0; i < CLEN; ++i) {
    float qt = qrow[i * 64];
    float pt = __shfl(pv, i);
    int st = __shfl(sv, i);
    float pre = pt * qt;
    float cer = st ? 0.f : er;
    float cei = st ? 0.f : ei;
    float nSr = cer * Sr - cei * Si + pre;
    Si = cer * Si + cei * Sr;
    Sr = nSr;
    float m2 = fmaf(Sr, Sr, Si * Si);
    float rsq = rsqrtf(fmaxf(m2, 1e-30f));
    float m = m2 * rsq;
    float sc = __log2f(1.0f + m) * 0.6931471805599453f * rsq;
    u32 pack = ((u32)f2bf_bits(sc * Sr) << 16) | (u32)f2bf_bits(sc * Si);
    srow[(size_t)i * 4096 + (Ldw ^ ((i & 7) << 2))] = pack;
  }
}

// ---------------- LN + LeakyReLU over bf16 split-K partials -> z0bf (unswizzled) ----------------
__global__ void ln_act16(const u16* __restrict__ parts, int KS, size_t pstride,
                         const float* __restrict__ bias, const float* __restrict__ gam,
                         const float* __restrict__ bet, u16* __restrict__ zbf) {
  __shared__ float red[8];
  int t = blockIdx.x, tid = threadIdx.x;
  size_t o = (size_t)t * D_DIM + tid;
  float v0 = bias[tid];
  float v1 = bias[tid + 256];
  for (int ks = 0; ks < KS; ++ks) {
    v0 += bf2f(parts[(size_t)ks * pstride + o]);
    v1 += bf2f(parts[(size_t)ks * pstride + o + 256]);
  }
  float s = wave_sum(v0 + v1);
  if ((tid & 63) == 0) red[tid >> 6] = s;
  __syncthreads();
  float mean = (red[0] + red[1] + red[2] + red[3]) * (1.f / 512.f);
  float d0 = v0 - mean, d1 = v1 - mean;
  float s2 = wave_sum(d0 * d0 + d1 * d1);
  if ((tid & 63) == 0) red[4 + (tid >> 6)] = s2;
  __syncthreads();
  float var = (red[4] + red[5] + red[6] + red[7]) * (1.f / 512.f);
  float rstd = rsqrtf(var + 1e-5f);
  float z0 = d0 * rstd * gam[tid] + bet[tid];
  float z1 = d1 * rstd * gam[tid + 256] + bet[tid + 256];
  z0 = z0 > 0.f ? z0 : 0.01f * z0;
  z1 = z1 > 0.f ? z1 : 0.01f * z1;
  zbf[o] = f2bf_bits(z0);
  zbf[o + 256] = f2bf_bits(z1);
}

// ---------------- LN + LeakyReLU over fp32 y (W1 epilogue) ----------------
__global__ void ln_act32(const float* __restrict__ y, const float* __restrict__ bias,
                         const float* __restrict__ gam, const float* __restrict__ bet,
                         const float* __restrict__ xsrc, float* __restrict__ xdst,
                         u16* __restrict__ xbf_next, float* __restrict__ finout) {
  __shared__ float red[8];
  int t = blockIdx.x, tid = threadIdx.x;
  size_t o = (size_t)t * D_DIM + tid;
  float v0 = y[o] + bias[tid];
  float v1 = y[o + 256] + bias[tid + 256];
  float s = wave_sum(v0 + v1);
  if ((tid & 63) == 0) red[tid >> 6] = s;
  __syncthreads();
  float mean = (red[0] + red[1] + red[2] + red[3]) * (1.f / 512.f);
  float d0 = v0 - mean, d1 = v1 - mean;
  float s2 = wave_sum(d0 * d0 + d1 * d1);
  if ((tid & 63) == 0) red[4 + (tid >> 6)] = s2;
  __syncthreads();
  float var = (red[4] + red[5] + red[6] + red[7]) * (1.f / 512.f);
  float rstd = rsqrtf(var + 1e-5f);
  float z0 = d0 * rstd * gam[tid] + bet[tid];
  float z1 = d1 * rstd * gam[tid + 256] + bet[tid + 256];
  z0 = z0 > 0.f ? z0 : 0.01f * z0;
  z1 = z1 > 0.f ? z1 : 0.01f * z1;
  if (xdst) {
    float x0 = xsrc[o] + z0, x1 = xsrc[o + 256] + z1;
    xdst[o] = x0;
    xdst[o + 256] = x1;
    xbf_next[o] = f2bf_bits(x0);
    xbf_next[o + 256] = f2bf_bits(x1);
  }
  if (finout) {
    finout[o] = z0;
    finout[o + 256] = z1;
  }
}

__global__ void err_signal(float* __restrict__ out, float code) {
  if (threadIdx.x == 0) out[0] = code;
}

// ---------------- host launch ----------------
extern "C" void kernel_launch(void* const* d_in, const int* in_sizes, int n_in, void* d_out,
                              int out_size, void* d_ws, size_t ws_size, hipStream_t stream) {
  const float* x_in = (const float*)d_in[0];
  const float* state = (const float*)d_in[1];
  const unsigned char* start8 = (const unsigned char*)d_in[2];
  const int* start32 = (const int*)d_in[2];
  const float* Wtr = (const float*)d_in[3];
  const float* Wc = (const float*)d_in[4];
  const float* a_in = (const float*)d_in[5];
  const float* b_in = (const float*)d_in[6];
  const float* W0 = (const float*)d_in[7];
  const float* b0 = (const float*)d_in[8];
  const float* g0 = (const float*)d_in[9];
  const float* beta0 = (const float*)d_in[10];
  const float* W1 = (const float*)d_in[11];
  const float* b1 = (const float*)d_in[12];
  const float* g1 = (const float*)d_in[13];
  const float* beta1 = (const float*)d_in[14];
  float* out = (float*)d_out;

  // one-time: allow 96 KiB dynamic LDS for the B-direct GEMM
  static int attr_state = 0;  // 0 unset, 1 ok, -1 failed
  if (attr_state == 0)
    attr_state = (hipFuncSetAttribute((const void*)gemm_8ph,
                                      hipFuncAttributeMaxDynamicSharedMemorySize,
                                      98304) == hipSuccess)
                     ? 1
                     : -1;
  const bool attr_ok = (attr_state == 1);

  char* w = (char*)d_ws;
  auto alloc = [&](size_t bytes) {
    char* ptr = w;
    w += (bytes + 255) & ~(size_t)255;
    return ptr;
  };
  float* x_ws = (float*)alloc(4ull * T_LEN * D_DIM);            // 8 MB
  u16* xbf = (u16*)alloc(2ull * T_LEN * D_DIM);                 // 4 MB
  u16* wcat = (u16*)alloc(2ull * 128 * D_DIM);                  // 128 KB
  u16* w0bf = (u16*)alloc(2ull * D_DIM * F_DIM);                // 8 MB (per-layer)
  u16* w1bf = (u16*)alloc(2ull * 3 * D_DIM * D_DIM);            // 1.5 MB (all layers)
  float* trct = (float*)alloc(4ull * T_LEN * 128);              // 2 MB
  float* pTbuf = (float*)alloc(4ull * T_LEN * 64);              // 1 MB
  float* qbuf = (float*)alloc(4ull * T_LEN * 64);               // 1 MB
  float4* chunkbuf = (float4*)alloc(16ull * NCHUNK * 64 * 64);  // 4 MB
  float2* s0buf = (float2*)alloc(8ull * NCHUNK * 64 * 64);      // 2 MB
  u16* z0bf = (u16*)alloc(2ull * T_LEN * D_DIM);                // 4 MB
  float* ybuf = (float*)alloc(4ull * T_LEN * D_DIM);            // 8 MB (W1 out)
  int* modep = (int*)alloc(256);
  size_t base1 = (size_t)(w - (char*)d_ws);

  if (n_in != 15) {
    err_signal<<<1, 64, 0, stream>>>(out, 9e6f + 1000.f * n_in);
    return;
  }
  const size_t MB = 1ull << 20;
  const size_t pstride = (size_t)T_LEN * D_DIM;  // elements per partial slab
  int KS, nseg;
  if (ws_size >= base1 + 16 * MB + 64 * MB) { KS = 4; nseg = 1; }
  else if (ws_size >= base1 + 16 * MB + 32 * MB) { KS = 4; nseg = 2; }
  else if (ws_size >= base1 + 8 * MB + 32 * MB) { KS = 2; nseg = 2; }
  else if (ws_size >= base1 + 8 * MB + 16 * MB) { KS = 2; nseg = 4; }
  else if (ws_size >= base1 + 4 * MB + 16 * MB) { KS = 1; nseg = 4; }
  else {
    err_signal<<<1, 64, 0, stream>>>(out, 9e6f);
    return;
  }
  const int seg_rows = T_LEN / nseg;
  const int seg_chunks = NCHUNK / nseg;
  u16* ypart = (u16*)alloc(2ull * KS * pstride);
  u16* scaled = (u16*)alloc(2ull * seg_rows * F_DIM);

  const bool use8 = (nseg == 1) && attr_ok;  // seg_rows==4096 -> grid.x=16

  detect_start<<<1, 256, 0, stream>>>(start8, modep);
  f2bf<<<(T_LEN * D_DIM) / 256, 256, 0, stream>>>(x_in, xbf, T_LEN * D_DIM);
  f2bf<<<(3 * D_DIM * D_DIM) / 256, 256, 0, stream>>>(W1, w1bf, 3 * D_DIM * D_DIM);

  for (int l = 0; l < 3; ++l) {
    const float* Wtr_l = Wtr + (size_t)l * 64 * D_DIM;
    const float* Wc_l = Wc + (size_t)l * 64 * D_DIM;
    const float* a_l = a_in + l * 64;
    const float* b_l = b_in + l * 64;
    const float* W0_l = W0 + (size_t)l * D_DIM * F_DIM;
    const u16* w1bf_l = w1bf + (size_t)l * D_DIM * D_DIM;
    const float* state_l = state + (size_t)l * 64 * 64;
    const float* xsrc = (l == 0) ? x_in : x_ws;

    k_conv<<<(128 * D_DIM + D_DIM * F_DIM) / 256, 256, 0, stream>>>(Wtr_l, Wc_l, wcat, W0_l,
                                                                    w0bf);
    // trct (4096 x 128) = xbf @ wcat^T
    gemm_bt<64, 64, 2, 2><<<dim3(T_LEN / 64, 2), 256, 0, stream>>>(xbf, wcat, trct, T_LEN, 128,
                                                                   D_DIM);
    prep_pq<<<T_LEN, 64, 0, stream>>>(trct, pTbuf, qbuf);
    scan_phase1<<<dim3(NCHUNK, 64), 64, 0, stream>>>(pTbuf, qbuf, start8, start32, modep, a_l,
                                                     b_l, chunkbuf);
    scan_phase2<<<64, 64, 0, stream>>>(chunkbuf, state_l, s0buf);

    for (int h = 0; h < nseg; ++h) {
      scan_phase3<<<dim3(seg_chunks, 64), 64, 0, stream>>>(pTbuf, qbuf, start8, start32, modep,
                                                           a_l, b_l, s0buf, (u32*)scaled,
                                                           h * seg_chunks);
      if (use8)
        gemm_8ph<<<dim3(seg_rows / 256, D_DIM / 128, KS), 512, 98304, stream>>>(
            scaled, w0bf, ypart + (size_t)h * seg_rows * D_DIM, pstride, D_DIM, F_DIM);
      else
        gemm128<<<dim3(seg_rows / 128, D_DIM / 128, KS), 256, 0, stream>>>(
            scaled, w0bf, ypart + (size_t)h * seg_rows * D_DIM, pstride, D_DIM, F_DIM);
    }
    ln_act16<<<T_LEN, 256, 0, stream>>>(ypart, KS, pstride, b0 + l * D_DIM, g0 + l * D_DIM,
                                        beta0 + l * D_DIM, z0bf);
    // y2 = z0 (4096x512) @ W1 (512x512)^T — no split-K, grid 64x8 = 512 blocks
    gemm_bt<64, 64, 2, 2><<<dim3(T_LEN / 64, D_DIM / 64), 256, 0, stream>>>(z0bf, w1bf_l, ybuf,
                                                                            T_LEN, D_DIM, D_DIM);
    ln_act32<<<T_LEN, 256, 0, stream>>>(ybuf, b1 + l * D_DIM, g1 + l * D_DIM, beta1 + l * D_DIM,
                                        (l < 2) ? xsrc : nullptr, (l < 2) ? x_ws : nullptr,
                                        (l < 2) ? xbf : nullptr, (l == 2) ? out : nullptr);
  }
}

// Round 7
// 484.546 us; speedup vs baseline: 1.1629x; 1.1325x over previous
//
#include <hip/hip_runtime.h>
#include <hip/hip_bf16.h>
#include <math.h>

#define T_LEN 4096
#define D_DIM 512
#define F_DIM 8192
#define NCHUNK 64
#define CLEN 64

typedef short short8 __attribute__((ext_vector_type(8)));
typedef float f32x4 __attribute__((ext_vector_type(4)));
typedef unsigned short u16;
typedef unsigned int u32;

// ---------------- helpers ----------------
__device__ inline float wave_sum(float v) {
#pragma unroll
  for (int o = 32; o; o >>= 1) v += __shfl_xor(v, o);
  return v;
}

__device__ inline u16 f2bf_bits(float v) {
  __hip_bfloat16 h = __float2bfloat16(v);
  return *(u16*)&h;
}

__device__ inline float bf2f(u16 u) {
  u32 x = ((u32)u) << 16;
  return *(float*)&x;
}

__device__ inline void gl_lds16(const void* g, void* l) {
  __builtin_amdgcn_global_load_lds((const __attribute__((address_space(1))) void*)g,
                                   (__attribute__((address_space(3))) void*)l, 16, 0, 0);
}

// start[] may arrive as 1-byte bools or int32 {0,1}.
__global__ void detect_start(const unsigned char* __restrict__ s8, int* __restrict__ mode) {
  __shared__ int found;
  if (threadIdx.x == 0) found = 0;
  __syncthreads();
  for (int i = threadIdx.x; i < 4096; i += 256)
    if ((i & 3) && s8[i]) found = 1;  // benign race, same value
  __syncthreads();
  if (threadIdx.x == 0) mode[0] = found;  // 1 = byte layout, 0 = int32 layout
}

__device__ inline int read_start(const unsigned char* s8, const int* s32, int mode, int t) {
  return mode ? (int)s8[t] : s32[t];
}

// ---------------- fp32 -> bf16(bits) convert (plain) ----------------
__global__ void f2bf(const float* __restrict__ s, u16* __restrict__ d, int n) {
  int i = blockIdx.x * 256 + threadIdx.x;
  if (i < n) d[i] = f2bf_bits(s[i]);
}

// fused per-layer weight conversion:
//   wcat = concat [Wtr_l; Wc_l] (128 x 512), unswizzled (BK=32 gemm)
//   w0bf: K-permute (f = r*128+2c+b <- b*4096+r*64+c) + granule swizzle by (d&7)
__global__ void k_conv(const float* __restrict__ wtr, const float* __restrict__ wc,
                       u16* __restrict__ wcat, const float* __restrict__ w0,
                       u16* __restrict__ w0bf) {
  int i = blockIdx.x * 256 + threadIdx.x;
  if (i < 128 * D_DIM) {
    float v = (i < 64 * D_DIM) ? wtr[i] : wc[i - 64 * D_DIM];
    wcat[i] = f2bf_bits(v);
  }
  int j = i - 128 * D_DIM;
  if (j >= 0 && j < D_DIM * F_DIM) {
    int d = j >> 13, f = j & 8191;
    int r = f >> 7, rem = f & 127;
    int c = rem >> 1, b = rem & 1;
    float v = w0[(size_t)d * 8192 + b * 4096 + r * 64 + c];
    w0bf[(size_t)d * 8192 + (f ^ ((d & 7) << 3))] = f2bf_bits(v);
  }
}

// ---------------- small MFMA GEMM (64x64 tile, BK=32, sync staging) — trct & W1 ----------------
template <int BM, int BN, int WR, int WC>
__global__ __launch_bounds__(256) void gemm_bt(const u16* __restrict__ A,
                                               const u16* __restrict__ B,
                                               float* __restrict__ C, int M, int N, int K) {
  constexpr int BK = 32;
  constexpr int MT = BM / (WR * 16);
  constexpr int NT = BN / (WC * 16);
  constexpr int AG = BM / 64;
  constexpr int BG = BN / 64;
  __shared__ u16 sA[BM * BK];
  __shared__ u16 sB[BN * BK];
  const int m0 = blockIdx.x * BM;
  const int n0 = blockIdx.y * BN;
  const int tid = threadIdx.x;
  const int wave = tid >> 6;
  const int lane = tid & 63;
  const int wr = wave / WC;
  const int wc = wave % WC;
  const int row_l = tid >> 2;
  const int c8 = (tid & 3) << 3;
  const int frow = lane & 15;
  const int fcol = (lane >> 4) << 3;

  f32x4 acc[MT][NT];
#pragma unroll
  for (int i = 0; i < MT; ++i)
#pragma unroll
    for (int j = 0; j < NT; ++j) acc[i][j] = (f32x4){0.f, 0.f, 0.f, 0.f};

  for (int k0 = 0; k0 < K; k0 += BK) {
#pragma unroll
    for (int j = 0; j < AG; ++j) {
      uint4 v = *(const uint4*)(A + (size_t)(m0 + j * 64 + row_l) * K + (k0 + c8));
      *(uint4*)(sA + (j * 64 + row_l) * BK + c8) = v;
    }
#pragma unroll
    for (int j = 0; j < BG; ++j) {
      uint4 v = *(const uint4*)(B + (size_t)(n0 + j * 64 + row_l) * K + (k0 + c8));
      *(uint4*)(sB + (j * 64 + row_l) * BK + c8) = v;
    }
    __syncthreads();
    short8 af[MT], bfr[NT];
#pragma unroll
    for (int i = 0; i < MT; ++i)
      af[i] = *(const short8*)(sA + (wr * MT * 16 + i * 16 + frow) * BK + fcol);
#pragma unroll
    for (int j = 0; j < NT; ++j)
      bfr[j] = *(const short8*)(sB + (wc * NT * 16 + j * 16 + frow) * BK + fcol);
#pragma unroll
    for (int i = 0; i < MT; ++i)
#pragma unroll
      for (int j = 0; j < NT; ++j)
        acc[i][j] = __builtin_amdgcn_mfma_f32_16x16x32_bf16(af[i], bfr[j], acc[i][j], 0, 0, 0);
    __syncthreads();
  }
#pragma unroll
  for (int i = 0; i < MT; ++i) {
    const int rbase = m0 + wr * MT * 16 + i * 16 + ((lane >> 4) << 2);
#pragma unroll
    for (int j = 0; j < NT; ++j) {
      const int col = n0 + wc * NT * 16 + j * 16 + (lane & 15);
#pragma unroll
      for (int rg = 0; rg < 4; ++rg) C[(size_t)(rbase + rg) * N + col] = acc[i][j][rg];
    }
  }
}

// ---------------- 128x128 MFMA GEMM, BK=64, XOR-swizzled operands, split-K, bf16 partials ----
// (retained for low-workspace fallback paths)
// A, B global layout: row-major with 16B granule g of each row stored at g ^ (row&7).
__global__ __launch_bounds__(256) void gemm128(const u16* __restrict__ A,
                                               const u16* __restrict__ B,
                                               u16* __restrict__ Cp, size_t pstride, int N,
                                               int Ktot) {
  __shared__ u16 sA[128 * 64];
  __shared__ u16 sB[128 * 64];
  const int tid = threadIdx.x;
  const int wave = tid >> 6;
  const int lane = tid & 63;
  const int wr = wave >> 1;
  const int wc = wave & 1;
  const int m0 = blockIdx.x * 128;
  const int n0 = blockIdx.y * 128;
  const int ks = blockIdx.z;
  const int Kper = Ktot / gridDim.z;
  const int kb = ks * Kper;
  const int row_s = tid >> 3;     // 0..31 staging row within 32-row group
  const int g8 = (tid & 7) << 3;  // granule offset (elems)
  const int frow = lane & 15;
  const int quad = lane >> 4;
  const int sw = frow & 7;

  f32x4 acc[4][4];
#pragma unroll
  for (int i = 0; i < 4; ++i)
#pragma unroll
    for (int j = 0; j < 4; ++j) acc[i][j] = (f32x4){0.f, 0.f, 0.f, 0.f};

  for (int k0 = kb; k0 < kb + Kper; k0 += 64) {
#pragma unroll
    for (int j = 0; j < 4; ++j) {
      gl_lds16(A + (size_t)(m0 + j * 32 + row_s) * Ktot + (k0 + g8), sA + j * 2048 + wave * 512);
      gl_lds16(B + (size_t)(n0 + j * 32 + row_s) * Ktot + (k0 + g8), sB + j * 2048 + wave * 512);
    }
    asm volatile("s_waitcnt vmcnt(0)" ::: "memory");
    __syncthreads();
#pragma unroll
    for (int kk = 0; kk < 2; ++kk) {
      const int gA = (((kk << 2) | quad) ^ sw) << 3;  // swizzled elem offset in row
      short8 af[4], bfr[4];
#pragma unroll
      for (int i = 0; i < 4; ++i)
        af[i] = *(const short8*)(sA + (wr * 64 + i * 16 + frow) * 64 + gA);
#pragma unroll
      for (int j = 0; j < 4; ++j)
        bfr[j] = *(const short8*)(sB + (wc * 64 + j * 16 + frow) * 64 + gA);
#pragma unroll
      for (int i = 0; i < 4; ++i)
#pragma unroll
        for (int j = 0; j < 4; ++j)
          acc[i][j] = __builtin_amdgcn_mfma_f32_16x16x32_bf16(af[i], bfr[j], acc[i][j], 0, 0, 0);
    }
    __syncthreads();
  }
#pragma unroll
  for (int i = 0; i < 4; ++i) {
    const int rbase = m0 + wr * 64 + i * 16 + ((lane >> 4) << 2);
#pragma unroll
    for (int j = 0; j < 4; ++j) {
      const int col = n0 + wc * 64 + j * 16 + (lane & 15);
#pragma unroll
      for (int rg = 0; rg < 4; ++rg)
        Cp[(size_t)ks * pstride + (size_t)(rbase + rg) * N + col] = f2bf_bits(acc[i][j][rg]);
    }
  }
}

// ---------------- 256x128 MFMA GEMM, merged 4-phase counted pipeline (v4 — best verified) ----
// R6 decision: B-direct (v5/v6) abandoned per tripwire — both regressed vs this structure.
// Geometry/swizzle/numerics as v2 (BM=256 BN=128 BK=64, 8 waves of 64x64, dbuf 96KiB, KS=4);
// quadrant pairs MERGED so each barrier-pair covers 16 MFMA/wave. Per iteration (2 K-tiles):
//  P0: 12 ds_reads (af_lo,bf0,bf1 of b0) | 6 gl_lds (tile-odd -> b1) | bar | lgkm0 | 16 MFMA
//  P1:  4 ds_reads (af_hi b0)                                        | bar | lgkm0 | 16 MFMA | vmcnt0
//  P2: 12 ds_reads (b1)  | if(nl) 6 gl_lds (next tile-even -> b0)    | bar | lgkm0 | 16 MFMA
//  P3:  4 ds_reads (af_hi b1)                                        | bar | lgkm0 | 16 MFMA | if(nl) vmcnt0
// Staged loads get a full ~2-phase window before their seal. WAR: stages only target
// buffers whose last reads completed before the preceding trailing barrier.
// Per-acc-element MFMA order identical to v2/v3 (q0->q1->q2->q3, kk ascending, bf16
// rounding at C-write) -> bit-identical output.
__global__ __launch_bounds__(512, 2) void gemm_8ph(const u16* __restrict__ A,
                                                   const u16* __restrict__ B,
                                                   u16* __restrict__ Cp, size_t pstride, int N,
                                                   int Ktot) {
  extern __shared__ u16 smem[];
  u16* sA = smem;          // [2][256*64]
  u16* sB = smem + 32768;  // [2][128*64]
  const int tid = threadIdx.x;
  const int wave = tid >> 6;
  const int lane = tid & 63;
  const int wr = wave >> 1;  // 0..3 -> 64-row group
  const int wc = wave & 1;   // 0..1 -> 64-col group
  const int m0 = blockIdx.x * 256;
  const int n0 = blockIdx.y * 128;
  const int ks = blockIdx.z;
  const int Kper = Ktot / gridDim.z;
  const int kb = ks * Kper;
  const int NITER = Kper >> 7;  // 128 K per iteration (2 x BK=64 tiles)
  const int r_l = tid >> 3;     // row within 64-row load group
  const int g8 = (tid & 7) << 3;
  const int frow = lane & 15;
  const int quad = lane >> 4;
  const int sw = frow & 7;
  const int o0 = (quad ^ sw) << 3;        // swizzled elem offset, kk=0
  const int o1 = ((4 | quad) ^ sw) << 3;  // swizzled elem offset, kk=1

  const u16* Abase = A + (size_t)(m0 + r_l) * Ktot + g8;
  const u16* Bbase = B + (size_t)(n0 + r_l) * Ktot + g8;

#define STAGE_A(l, k0, b) \
  gl_lds16(Abase + (size_t)(l) * 64 * Ktot + (k0), sA + (b)*16384 + (l)*4096 + wave * 512)
#define STAGE_B(l, k0, b) \
  gl_lds16(Bbase + (size_t)(l) * 64 * Ktot + (k0), sB + (b)*8192 + (l)*4096 + wave * 512)
// 4x ds_read_b128: A frags (2 m-frags x kk=0,1) for row-half qm_ of this wave's 64 rows
#define RD_A(dst, b, qm_)                                               \
  do {                                                                  \
    const u16* _p = sA + (b)*16384 + (wr * 64 + (qm_)*32 + frow) * 64;  \
    dst[0][0] = *(const short8*)(_p + o0);                              \
    dst[0][1] = *(const short8*)(_p + o1);                              \
    dst[1][0] = *(const short8*)(_p + 1024 + o0);                       \
    dst[1][1] = *(const short8*)(_p + 1024 + o1);                       \
  } while (0)
// 4x ds_read_b128: B frags (2 n-frags x kk=0,1) for col-half half_ of this wave's 64 cols
#define RD_B(dst, b, half_)                                              \
  do {                                                                   \
    const u16* _p = sB + (b)*8192 + (wc * 64 + (half_)*32 + frow) * 64;  \
    dst[0][0] = *(const short8*)(_p + o0);                               \
    dst[0][1] = *(const short8*)(_p + o1);                               \
    dst[1][0] = *(const short8*)(_p + 1024 + o0);                        \
    dst[1][1] = *(const short8*)(_p + 1024 + o1);                        \
  } while (0)
// 16 MFMA: two quadrants (rows qm_*32.., cols 0..31 via b0_ then 32..63 via b1_)
#define MFMA_QPAIR(ar, b0_, b1_, qm_)                                               \
  do {                                                                              \
    _Pragma("unroll") for (int f = 0; f < 2; ++f) _Pragma("unroll") for (int g = 0; \
                                                                         g < 2;    \
                                                                         ++g)      \
        _Pragma("unroll") for (int kk = 0; kk < 2; ++kk) acc[(qm_)*2 + f][g] =      \
            __builtin_amdgcn_mfma_f32_16x16x32_bf16(ar[f][kk], b0_[g][kk],          \
                                                    acc[(qm_)*2 + f][g], 0, 0, 0); \
    _Pragma("unroll") for (int f = 0; f < 2; ++f) _Pragma("unroll") for (int g = 0; \
                                                                         g < 2;    \
                                                                         ++g)      \
        _Pragma("unroll") for (int kk = 0; kk < 2; ++kk) acc[(qm_)*2 + f][2 + g] =  \
            __builtin_amdgcn_mfma_f32_16x16x32_bf16(ar[f][kk], b1_[g][kk],          \
                                                    acc[(qm_)*2 + f][2 + g], 0, 0,  \
                                                    0);                             \
  } while (0)

  f32x4 acc[4][4];
#pragma unroll
  for (int i = 0; i < 4; ++i)
#pragma unroll
    for (int j = 0; j < 4; ++j) acc[i][j] = (f32x4){0.f, 0.f, 0.f, 0.f};

  short8 af_lo[2][2];  // A rows 0..31 of wave's 64 (current tile)
  short8 af_hi[2][2];  // A rows 32..63
  short8 bfr0[2][2];   // B cols 0..31 of wave's 64
  short8 bfr1[2][2];   // B cols 32..63

  // Prologue: stage tile0 -> b0, seal.
  STAGE_A(0, kb, 0);
  STAGE_A(1, kb, 0);
  STAGE_A(2, kb, 0);
  STAGE_A(3, kb, 0);
  STAGE_B(0, kb, 0);
  STAGE_B(1, kb, 0);
  asm volatile("s_waitcnt vmcnt(0)" ::: "memory");
  __builtin_amdgcn_s_barrier();

  for (int I = 0; I < NITER; ++I) {
    const int k0e = kb + (I << 7);  // even tile k-offset
    const bool nl = (I < NITER - 1);

    // ---- P0: even tile (b0), quadrants q0,q1 ----
    RD_A(af_lo, 0, 0);
    RD_B(bfr0, 0, 0);
    RD_B(bfr1, 0, 1);
    // stage odd tile -> b1 (b1's last reads completed before prev P3's trailing barrier)
    STAGE_A(0, k0e + 64, 1);
    STAGE_A(1, k0e + 64, 1);
    STAGE_A(2, k0e + 64, 1);
    STAGE_A(3, k0e + 64, 1);
    STAGE_B(0, k0e + 64, 1);
    STAGE_B(1, k0e + 64, 1);
    __builtin_amdgcn_s_barrier();
    asm volatile("s_waitcnt lgkmcnt(0)" ::: "memory");
    __builtin_amdgcn_sched_barrier(0);
    __builtin_amdgcn_s_setprio(1);
    MFMA_QPAIR(af_lo, bfr0, bfr1, 0);
    __builtin_amdgcn_s_setprio(0);
    __builtin_amdgcn_s_barrier();

    // ---- P1: even tile (b0), quadrants q2,q3 ----
    RD_A(af_hi, 0, 1);
    __builtin_amdgcn_s_barrier();
    asm volatile("s_waitcnt lgkmcnt(0)" ::: "memory");
    __builtin_amdgcn_sched_barrier(0);
    __builtin_amdgcn_s_setprio(1);
    // q2 (cols 32..63) first, then q3 (cols 0..31) — same per-acc order as v2/v3
#pragma unroll
    for (int f = 0; f < 2; ++f)
#pragma unroll
      for (int g = 0; g < 2; ++g)
#pragma unroll
        for (int kk = 0; kk < 2; ++kk)
          acc[2 + f][2 + g] = __builtin_amdgcn_mfma_f32_16x16x32_bf16(
              af_hi[f][kk], bfr1[g][kk], acc[2 + f][2 + g], 0, 0, 0);
#pragma unroll
    for (int f = 0; f < 2; ++f)
#pragma unroll
      for (int g = 0; g < 2; ++g)
#pragma unroll
        for (int kk = 0; kk < 2; ++kk)
          acc[2 + f][g] = __builtin_amdgcn_mfma_f32_16x16x32_bf16(af_hi[f][kk], bfr0[g][kk],
                                                                  acc[2 + f][g], 0, 0, 0);
    __builtin_amdgcn_s_setprio(0);
    asm volatile("s_waitcnt vmcnt(0)" ::: "memory");  // seal b1 (staged at P0, ~2-phase slack)
    __builtin_amdgcn_s_barrier();

    // ---- P2: odd tile (b1), quadrants q0,q1 ----
    RD_A(af_lo, 1, 0);
    RD_B(bfr0, 1, 0);
    RD_B(bfr1, 1, 1);
    if (nl) {  // stage next even tile -> b0 (b0's last reads completed before P1's barrier)
      STAGE_A(0, k0e + 128, 0);
      STAGE_A(1, k0e + 128, 0);
      STAGE_A(2, k0e + 128, 0);
      STAGE_A(3, k0e + 128, 0);
      STAGE_B(0, k0e + 128, 0);
      STAGE_B(1, k0e + 128, 0);
    }
    __builtin_amdgcn_s_barrier();
    asm volatile("s_waitcnt lgkmcnt(0)" ::: "memory");
    __builtin_amdgcn_sched_barrier(0);
    __builtin_amdgcn_s_setprio(1);
    MFMA_QPAIR(af_lo, bfr0, bfr1, 0);
    __builtin_amdgcn_s_setprio(0);
    __builtin_amdgcn_s_barrier();

    // ---- P3: odd tile (b1), quadrants q2,q3 ----
    RD_A(af_hi, 1, 1);
    __builtin_amdgcn_s_barrier();
    asm volatile("s_waitcnt lgkmcnt(0)" ::: "memory");
    __builtin_amdgcn_sched_barrier(0);
    __builtin_amdgcn_s_setprio(1);
#pragma unroll
    for (int f = 0; f < 2; ++f)
#pragma unroll
      for (int g = 0; g < 2; ++g)
#pragma unroll
        for (int kk = 0; kk < 2; ++kk)
          acc[2 + f][2 + g] = __builtin_amdgcn_mfma_f32_16x16x32_bf16(
              af_hi[f][kk], bfr1[g][kk], acc[2 + f][2 + g], 0, 0, 0);
#pragma unroll
    for (int f = 0; f < 2; ++f)
#pragma unroll
      for (int g = 0; g < 2; ++g)
#pragma unroll
        for (int kk = 0; kk < 2; ++kk)
          acc[2 + f][g] = __builtin_amdgcn_mfma_f32_16x16x32_bf16(af_hi[f][kk], bfr0[g][kk],
                                                                  acc[2 + f][g], 0, 0, 0);
    __builtin_amdgcn_s_setprio(0);
    if (nl) asm volatile("s_waitcnt vmcnt(0)" ::: "memory");  // seal b0 (staged at P2)
    __builtin_amdgcn_s_barrier();
  }
#undef STAGE_A
#undef STAGE_B
#undef RD_A
#undef RD_B
#undef MFMA_QPAIR

#pragma unroll
  for (int i = 0; i < 4; ++i) {
    const int rbase = m0 + wr * 64 + i * 16 + (quad << 2);
#pragma unroll
    for (int j = 0; j < 4; ++j) {
      const int col = n0 + wc * 64 + j * 16 + frow;
#pragma unroll
      for (int rg = 0; rg < 4; ++rg)
        Cp[(size_t)ks * pstride + (size_t)(rbase + rg) * N + col] = f2bf_bits(acc[i][j][rg]);
    }
  }
}

// ---------------- p/q prep: pT=|tr| transposed, q=|ct|/(1e-8+Sp*Sq) ----------------
__global__ void prep_pq(const float* __restrict__ trct, float* __restrict__ pT,
                        float* __restrict__ q) {
  int t = blockIdx.x;
  int lane = threadIdx.x;  // 64
  float tr = trct[t * 128 + lane];
  float ct = trct[t * 128 + 64 + lane];
  float ap = fabsf(tr), aq = fabsf(ct);
  float Sp = wave_sum(ap);
  float Sq = wave_sum(aq);
  float denom = 1e-8f + Sp * Sq;
  pT[lane * T_LEN + t] = ap;  // transposed for shuffle-broadcast in scans
  q[t * 64 + lane] = aq / denom;
}

// ---------------- scan phase 1: per-chunk affine summary (A,B) ----------------
__global__ void scan_phase1(const float* __restrict__ pT, const float* __restrict__ q,
                            const unsigned char* __restrict__ st8, const int* __restrict__ st32,
                            const int* __restrict__ modep, const float* __restrict__ a,
                            const float* __restrict__ b, float4* __restrict__ chunkbuf) {
  int chunk = blockIdx.x, r = blockIdx.y, c = threadIdx.x;
  int mode = modep[0];
  int t0 = chunk * CLEN;
  float na = -fabsf(a[r]);
  float rho = __expf(na);
  float bb = b[c];
  float er = rho * __cosf(bb), ei = rho * __sinf(bb);
  float pv = pT[r * T_LEN + t0 + c];             // lane c holds p for step c
  int sv = read_start(st8, st32, mode, t0 + c);  // lane c holds start for step c
  unsigned long long bal = __ballot(sv != 0);
  float Ar, Ai;
  if (bal) {
    Ar = 0.f; Ai = 0.f;
  } else {
    float mag = __expf(64.f * na);
    float ang = 64.f * bb;
    Ar = mag * __cosf(ang);
    Ai = mag * __sinf(ang);
  }
  int L = bal ? (63 - __builtin_clzll(bal)) : 0;  // wave-uniform
  float Br = 0.f, Bi = 0.f;
  const float* qrow = q + (size_t)t0 * 64 + c;
  for (int i = L; i < CLEN; ++i) {
    float pre = __shfl(pv, i) * qrow[i * 64];
    float nBr = er * Br - ei * Bi + pre;
    Bi = er * Bi + ei * Br;
    Br = nBr;
  }
  chunkbuf[((size_t)chunk * 64 + r) * 64 + c] = make_float4(Ar, Ai, Br, Bi);
}

// ---------------- scan phase 2: sequential chunk combine ----------------
__global__ void scan_phase2(const float4* __restrict__ chunkbuf, const float* __restrict__ state,
                            float2* __restrict__ s0buf) {
  int r = blockIdx.x, c = threadIdx.x;
  float Sr = state[r * 64 + c], Si = 0.f;
  for (int k = 0; k < NCHUNK; ++k) {
    s0buf[((size_t)k * 64 + r) * 64 + c] = make_float2(Sr, Si);
    float4 ab = chunkbuf[((size_t)k * 64 + r) * 64 + c];
    float nSr = ab.x * Sr - ab.y * Si + ab.z;
    Si = ab.x * Si + ab.y * Sr + ab.w;
    Sr = nSr;
  }
}

// ---------------- scan phase 3: replay + packed log-polar features (swizzled store) ----
__global__ void scan_phase3(const float* __restrict__ pT, const float* __restrict__ q,
                            const unsigned char* __restrict__ st8, const int* __restrict__ st32,
                            const int* __restrict__ modep, const float* __restrict__ a,
                            const float* __restrict__ b, const float2* __restrict__ s0buf,
                            u32* __restrict__ scaled, int c0) {
  int chunk = c0 + blockIdx.x, r = blockIdx.y, c = threadIdx.x;
  int mode = modep[0];
  int t0 = chunk * CLEN;
  float rho = __expf(-fabsf(a[r]));
  float bb = b[c];
  float er = rho * __cosf(bb), ei = rho * __sinf(bb);
  float pv = pT[r * T_LEN + t0 + c];
  int sv = read_start(st8, st32, mode, t0 + c);
  float2 s0 = s0buf[((size_t)chunk * 64 + r) * 64 + c];
  float Sr = s0.x, Si = s0.y;
  int tl0 = (chunk - c0) * CLEN;
  const float* qrow = q + (size_t)t0 * 64 + c;
  u32* srow = scaled + (size_t)tl0 * 4096;
  const int Ldw = r * 64 + c;
#pragma unroll 4
  for (int i = 0; i < CLEN; ++i) {
    float qt = qrow[i * 64];
    float pt = __shfl(pv, i);
    int st = __shfl(sv, i);
    float pre = pt * qt;
    float cer = st ? 0.f : er;
    float cei = st ? 0.f : ei;
    float nSr = cer * Sr - cei * Si + pre;
    Si = cer * Si + cei * Sr;
    Sr = nSr;
    float m2 = fmaf(Sr, Sr, Si * Si);
    float rsq = rsqrtf(fmaxf(m2, 1e-30f));
    float m = m2 * rsq;
    float sc = __log2f(1.0f + m) * 0.6931471805599453f * rsq;
    u32 pack = ((u32)f2bf_bits(sc * Sr) << 16) | (u32)f2bf_bits(sc * Si);
    srow[(size_t)i * 4096 + (Ldw ^ ((i & 7) << 2))] = pack;
  }
}

// ---------------- LN + LeakyReLU over bf16 split-K partials -> z0bf (vectorized, 1 wave/row) ----
// G13: old version did scalar bf16 loads (2B/lane). Now 64 lanes x 8 elems: short8 loads
// (16B/lane), float4 param loads, pure wave-shuffle reductions (no LDS, no syncthreads).
__global__ void ln_act16(const u16* __restrict__ parts, int KS, size_t pstride,
                         const float* __restrict__ bias, const float* __restrict__ gam,
                         const float* __restrict__ bet, u16* __restrict__ zbf) {
  int t = blockIdx.x, lane = threadIdx.x;  // 64 lanes
  int e0 = lane << 3;
  size_t o = (size_t)t * D_DIM + e0;
  float4 ba = *(const float4*)(bias + e0);
  float4 bb4 = *(const float4*)(bias + e0 + 4);
  float v[8] = {ba.x, ba.y, ba.z, ba.w, bb4.x, bb4.y, bb4.z, bb4.w};
  for (int ks = 0; ks < KS; ++ks) {
    short8 p = *(const short8*)(parts + (size_t)ks * pstride + o);
#pragma unroll
    for (int j = 0; j < 8; ++j) v[j] += bf2f((u16)p[j]);
  }
  float s8 = 0.f;
#pragma unroll
  for (int j = 0; j < 8; ++j) s8 += v[j];
  float mean = wave_sum(s8) * (1.f / 512.f);
  float d[8];
  float sq = 0.f;
#pragma unroll
  for (int j = 0; j < 8; ++j) {
    d[j] = v[j] - mean;
    sq = fmaf(d[j], d[j], sq);
  }
  float var = wave_sum(sq) * (1.f / 512.f);
  float rstd = rsqrtf(var + 1e-5f);
  float4 g0v = *(const float4*)(gam + e0);
  float4 g1v = *(const float4*)(gam + e0 + 4);
  float4 t0v = *(const float4*)(bet + e0);
  float4 t1v = *(const float4*)(bet + e0 + 4);
  float gg[8] = {g0v.x, g0v.y, g0v.z, g0v.w, g1v.x, g1v.y, g1v.z, g1v.w};
  float tt[8] = {t0v.x, t0v.y, t0v.z, t0v.w, t1v.x, t1v.y, t1v.z, t1v.w};
  short8 r;
#pragma unroll
  for (int j = 0; j < 8; ++j) {
    float z = d[j] * rstd * gg[j] + tt[j];
    z = z > 0.f ? z : 0.01f * z;
    r[j] = (short)f2bf_bits(z);
  }
  *(short8*)(zbf + o) = r;
}

// ---------------- LN + LeakyReLU over fp32 y (W1 epilogue; vectorized, 1 wave/row) ----------
__global__ void ln_act32(const float* __restrict__ y, const float* __restrict__ bias,
                         const float* __restrict__ gam, const float* __restrict__ bet,
                         const float* __restrict__ xsrc, float* __restrict__ xdst,
                         u16* __restrict__ xbf_next, float* __restrict__ finout) {
  int t = blockIdx.x, lane = threadIdx.x;  // 64 lanes
  int e0 = lane << 3;
  size_t o = (size_t)t * D_DIM + e0;
  float4 y0 = *(const float4*)(y + o);
  float4 y1 = *(const float4*)(y + o + 4);
  float4 ba = *(const float4*)(bias + e0);
  float4 bb4 = *(const float4*)(bias + e0 + 4);
  float v[8] = {y0.x + ba.x, y0.y + ba.y, y0.z + ba.z, y0.w + ba.w,
                y1.x + bb4.x, y1.y + bb4.y, y1.z + bb4.z, y1.w + bb4.w};
  float s8 = 0.f;
#pragma unroll
  for (int j = 0; j < 8; ++j) s8 += v[j];
  float mean = wave_sum(s8) * (1.f / 512.f);
  float d[8];
  float sq = 0.f;
#pragma unroll
  for (int j = 0; j < 8; ++j) {
    d[j] = v[j] - mean;
    sq = fmaf(d[j], d[j], sq);
  }
  float var = wave_sum(sq) * (1.f / 512.f);
  float rstd = rsqrtf(var + 1e-5f);
  float4 g0v = *(const float4*)(gam + e0);
  float4 g1v = *(const float4*)(gam + e0 + 4);
  float4 t0v = *(const float4*)(bet + e0);
  float4 t1v = *(const float4*)(bet + e0 + 4);
  float gg[8] = {g0v.x, g0v.y, g0v.z, g0v.w, g1v.x, g1v.y, g1v.z, g1v.w};
  float tt[8] = {t0v.x, t0v.y, t0v.z, t0v.w, t1v.x, t1v.y, t1v.z, t1v.w};
  float z[8];
#pragma unroll
  for (int j = 0; j < 8; ++j) {
    float zz = d[j] * rstd * gg[j] + tt[j];
    z[j] = zz > 0.f ? zz : 0.01f * zz;
  }
  if (xdst) {
    float4 x0 = *(const float4*)(xsrc + o);
    float4 x1 = *(const float4*)(xsrc + o + 4);
    float xx[8] = {x0.x + z[0], x0.y + z[1], x0.z + z[2], x0.w + z[3],
                   x1.x + z[4], x1.y + z[5], x1.z + z[6], x1.w + z[7]};
    *(float4*)(xdst + o) = make_float4(xx[0], xx[1], xx[2], xx[3]);
    *(float4*)(xdst + o + 4) = make_float4(xx[4], xx[5], xx[6], xx[7]);
    short8 r;
#pragma unroll
    for (int j = 0; j < 8; ++j) r[j] = (short)f2bf_bits(xx[j]);
    *(short8*)(xbf_next + o) = r;
  }
  if (finout) {
    *(float4*)(finout + o) = make_float4(z[0], z[1], z[2], z[3]);
    *(float4*)(finout + o + 4) = make_float4(z[4], z[5], z[6], z[7]);
  }
}

__global__ void err_signal(float* __restrict__ out, float code) {
  if (threadIdx.x == 0) out[0] = code;
}

// ---------------- host launch ----------------
extern "C" void kernel_launch(void* const* d_in, const int* in_sizes, int n_in, void* d_out,
                              int out_size, void* d_ws, size_t ws_size, hipStream_t stream) {
  const float* x_in = (const float*)d_in[0];
  const float* state = (const float*)d_in[1];
  const unsigned char* start8 = (const unsigned char*)d_in[2];
  const int* start32 = (const int*)d_in[2];
  const float* Wtr = (const float*)d_in[3];
  const float* Wc = (const float*)d_in[4];
  const float* a_in = (const float*)d_in[5];
  const float* b_in = (const float*)d_in[6];
  const float* W0 = (const float*)d_in[7];
  const float* b0 = (const float*)d_in[8];
  const float* g0 = (const float*)d_in[9];
  const float* beta0 = (const float*)d_in[10];
  const float* W1 = (const float*)d_in[11];
  const float* b1 = (const float*)d_in[12];
  const float* g1 = (const float*)d_in[13];
  const float* beta1 = (const float*)d_in[14];
  float* out = (float*)d_out;

  // one-time: allow 96 KiB dynamic LDS for the merged-phase GEMM
  static int attr_state = 0;  // 0 unset, 1 ok, -1 failed
  if (attr_state == 0)
    attr_state = (hipFuncSetAttribute((const void*)gemm_8ph,
                                      hipFuncAttributeMaxDynamicSharedMemorySize,
                                      98304) == hipSuccess)
                     ? 1
                     : -1;
  const bool attr_ok = (attr_state == 1);

  char* w = (char*)d_ws;
  auto alloc = [&](size_t bytes) {
    char* ptr = w;
    w += (bytes + 255) & ~(size_t)255;
    return ptr;
  };
  float* x_ws = (float*)alloc(4ull * T_LEN * D_DIM);            // 8 MB
  u16* xbf = (u16*)alloc(2ull * T_LEN * D_DIM);                 // 4 MB
  u16* wcat = (u16*)alloc(2ull * 128 * D_DIM);                  // 128 KB
  u16* w0bf = (u16*)alloc(2ull * D_DIM * F_DIM);                // 8 MB (per-layer)
  u16* w1bf = (u16*)alloc(2ull * 3 * D_DIM * D_DIM);            // 1.5 MB (all layers)
  float* trct = (float*)alloc(4ull * T_LEN * 128);              // 2 MB
  float* pTbuf = (float*)alloc(4ull * T_LEN * 64);              // 1 MB
  float* qbuf = (float*)alloc(4ull * T_LEN * 64);               // 1 MB
  float4* chunkbuf = (float4*)alloc(16ull * NCHUNK * 64 * 64);  // 4 MB
  float2* s0buf = (float2*)alloc(8ull * NCHUNK * 64 * 64);      // 2 MB
  u16* z0bf = (u16*)alloc(2ull * T_LEN * D_DIM);                // 4 MB
  float* ybuf = (float*)alloc(4ull * T_LEN * D_DIM);            // 8 MB (W1 out)
  int* modep = (int*)alloc(256);
  size_t base1 = (size_t)(w - (char*)d_ws);

  if (n_in != 15) {
    err_signal<<<1, 64, 0, stream>>>(out, 9e6f + 1000.f * n_in);
    return;
  }
  const size_t MB = 1ull << 20;
  const size_t pstride = (size_t)T_LEN * D_DIM;  // elements per partial slab
  int KS, nseg;
  if (ws_size >= base1 + 16 * MB + 64 * MB) { KS = 4; nseg = 1; }
  else if (ws_size >= base1 + 16 * MB + 32 * MB) { KS = 4; nseg = 2; }
  else if (ws_size >= base1 + 8 * MB + 32 * MB) { KS = 2; nseg = 2; }
  else if (ws_size >= base1 + 8 * MB + 16 * MB) { KS = 2; nseg = 4; }
  else if (ws_size >= base1 + 4 * MB + 16 * MB) { KS = 1; nseg = 4; }
  else {
    err_signal<<<1, 64, 0, stream>>>(out, 9e6f);
    return;
  }
  const int seg_rows = T_LEN / nseg;
  const int seg_chunks = NCHUNK / nseg;
  u16* ypart = (u16*)alloc(2ull * KS * pstride);
  u16* scaled = (u16*)alloc(2ull * seg_rows * F_DIM);

  const bool use8 = (nseg == 1) && attr_ok;  // seg_rows==4096 -> grid.x=16

  detect_start<<<1, 256, 0, stream>>>(start8, modep);
  f2bf<<<(T_LEN * D_DIM) / 256, 256, 0, stream>>>(x_in, xbf, T_LEN * D_DIM);
  f2bf<<<(3 * D_DIM * D_DIM) / 256, 256, 0, stream>>>(W1, w1bf, 3 * D_DIM * D_DIM);

  for (int l = 0; l < 3; ++l) {
    const float* Wtr_l = Wtr + (size_t)l * 64 * D_DIM;
    const float* Wc_l = Wc + (size_t)l * 64 * D_DIM;
    const float* a_l = a_in + l * 64;
    const float* b_l = b_in + l * 64;
    const float* W0_l = W0 + (size_t)l * D_DIM * F_DIM;
    const u16* w1bf_l = w1bf + (size_t)l * D_DIM * D_DIM;
    const float* state_l = state + (size_t)l * 64 * 64;
    const float* xsrc = (l == 0) ? x_in : x_ws;

    k_conv<<<(128 * D_DIM + D_DIM * F_DIM) / 256, 256, 0, stream>>>(Wtr_l, Wc_l, wcat, W0_l,
                                                                    w0bf);
    // trct (4096 x 128) = xbf @ wcat^T
    gemm_bt<64, 64, 2, 2><<<dim3(T_LEN / 64, 2), 256, 0, stream>>>(xbf, wcat, trct, T_LEN, 128,
                                                                   D_DIM);
    prep_pq<<<T_LEN, 64, 0, stream>>>(trct, pTbuf, qbuf);
    scan_phase1<<<dim3(NCHUNK, 64), 64, 0, stream>>>(pTbuf, qbuf, start8, start32, modep, a_l,
                                                     b_l, chunkbuf);
    scan_phase2<<<64, 64, 0, stream>>>(chunkbuf, state_l, s0buf);

    for (int h = 0; h < nseg; ++h) {
      scan_phase3<<<dim3(seg_chunks, 64), 64, 0, stream>>>(pTbuf, qbuf, start8, start32, modep,
                                                           a_l, b_l, s0buf, (u32*)scaled,
                                                           h * seg_chunks);
      if (use8)
        gemm_8ph<<<dim3(seg_rows / 256, D_DIM / 128, KS), 512, 98304, stream>>>(
            scaled, w0bf, ypart + (size_t)h * seg_rows * D_DIM, pstride, D_DIM, F_DIM);
      else
        gemm128<<<dim3(seg_rows / 128, D_DIM / 128, KS), 256, 0, stream>>>(
            scaled, w0bf, ypart + (size_t)h * seg_rows * D_DIM, pstride, D_DIM, F_DIM);
    }
    ln_act16<<<T_LEN, 64, 0, stream>>>(ypart, KS, pstride, b0 + l * D_DIM, g0 + l * D_DIM,
                                       beta0 + l * D_DIM, z0bf);
    // y2 = z0 (4096x512) @ W1 (512x512)^T — no split-K, grid 64x8 = 512 blocks
    gemm_bt<64, 64, 2, 2><<<dim3(T_LEN / 64, D_DIM / 64), 256, 0, stream>>>(z0bf, w1bf_l, ybuf,
                                                                            T_LEN, D_DIM, D_DIM);
    ln_act32<<<T_LEN, 64, 0, stream>>>(ybuf, b1 + l * D_DIM, g1 + l * D_DIM, beta1 + l * D_DIM,
                                       (l < 2) ? xsrc : nullptr, (l < 2) ? x_ws : nullptr,
                                       (l < 2) ? xbf : nullptr, (l == 2) ? out : nullptr);
  }
}